// Round 2
// baseline (1853.887 us; speedup 1.0000x reference)
//
#include <hip/hip_runtime.h>

#define N_NODES 50000
#define N_EDGES 800000
#define LRELU_SLOPE 0.2f
#define BN_EPS 1e-5f

__device__ __forceinline__ float lrelu(float x){ return fmaxf(x,0.f) + LRELU_SLOPE*fminf(x,0.f); }
__device__ __forceinline__ float wsum(float v){
  #pragma unroll
  for(int m=32;m>=1;m>>=1) v += __shfl_xor(v, m, 64);
  return v;
}

// ---------------- CSR build ----------------
__global__ __launch_bounds__(256) void k_init(int* __restrict__ cnt, int* __restrict__ fill,
                                              int* __restrict__ gstart, int* __restrict__ gend){
  int i = blockIdx.x*256 + threadIdx.x;
  if(i < N_NODES){ cnt[i] = 0; fill[i] = 0; }
  if(i < 64){ gstart[i] = N_NODES; gend[i] = 0; }
}

__global__ __launch_bounds__(256) void k_hist(const int* __restrict__ eidx, int* __restrict__ cnt){
  int e = blockIdx.x*256 + threadIdx.x;
  if(e < N_EDGES) atomicAdd(&cnt[eidx[N_EDGES + e]], 1);
}

__global__ __launch_bounds__(1024) void k_scan(const int* __restrict__ cnt, int* __restrict__ rowptr){
  __shared__ int part[1024];
  int t = threadIdx.x;
  const int per = (N_NODES + 1023)/1024; // 49
  int beg = t*per, end = beg+per; if(end > N_NODES) end = N_NODES;
  int s = 0;
  for(int i=beg;i<end;i++) s += cnt[i];
  part[t] = s;
  __syncthreads();
  for(int off=1; off<1024; off<<=1){
    int v = (t>=off) ? part[t-off] : 0;
    __syncthreads();
    part[t] += v;
    __syncthreads();
  }
  int run = (t==0) ? 0 : part[t-1];
  for(int i=beg;i<end;i++){ rowptr[i] = run; run += cnt[i]; }
  if(t==1023) rowptr[N_NODES] = run;
}

__global__ __launch_bounds__(256) void k_scatter(const int* __restrict__ eidx, const float* __restrict__ pw,
                                                 const int* __restrict__ rowptr, int* __restrict__ fill,
                                                 int* __restrict__ s_src, float* __restrict__ s_w){
  int e = blockIdx.x*256 + threadIdx.x;
  if(e < N_EDGES){
    int d = eidx[N_EDGES + e];
    int pos = rowptr[d] + atomicAdd(&fill[d], 1);
    s_src[pos] = eidx[e];
    s_w[pos]   = pw[e];
  }
}

// ---------------- GCN ----------------
__global__ __launch_bounds__(256) void k_deg(const int* __restrict__ rowptr, const float* __restrict__ s_w,
                                             float* __restrict__ dinv){
  int n = blockIdx.x*256 + threadIdx.x;
  if(n >= N_NODES) return;
  int rb = rowptr[n], re = rowptr[n+1];
  float d = 1.f; // self-loop weight
  for(int j=rb;j<re;j++) d += s_w[j];
  dinv[n] = 1.f / sqrtf(d);
}

__global__ __launch_bounds__(256) void k_enorm(const int* __restrict__ s_src, const float* __restrict__ s_w,
                                               const float* __restrict__ dinv, float* __restrict__ g_e){
  int j = blockIdx.x*256 + threadIdx.x;
  if(j < N_EDGES) g_e[j] = dinv[s_src[j]] * s_w[j];
}

__global__ __launch_bounds__(256) void k_h(const float* __restrict__ px, const float* __restrict__ gw,
                                           float* __restrict__ h){
  int n = blockIdx.x*256 + threadIdx.x;
  if(n >= N_NODES) return;
  float x[33];
  #pragma unroll
  for(int k=0;k<33;k++) x[k] = px[n*33+k];
  for(int c=0;c<33;c++){
    float a = 0.f;
    #pragma unroll
    for(int k=0;k<33;k++) a = fmaf(x[k], gw[c*33+k], a);
    h[n*33+c] = a;
  }
}

// xp1 padded to stride 36, fused: agg + gcn_b + relu + BN(eval)
__global__ __launch_bounds__(256) void k_gcn(const float* __restrict__ h, const int* __restrict__ rowptr,
                                             const int* __restrict__ s_src, const float* __restrict__ g_e,
                                             const float* __restrict__ dinv,
                                             const float* __restrict__ gcnb, const float* __restrict__ bnm,
                                             const float* __restrict__ bnv, const float* __restrict__ bnw,
                                             const float* __restrict__ bnb, float* __restrict__ xp1){
  int t = threadIdx.x;
  int nl = t/33, c = t - nl*33;
  int n = blockIdx.x*7 + nl;
  if(nl < 7 && n < N_NODES){
    float acc = 0.f;
    int rb = rowptr[n], re = rowptr[n+1];
    for(int j=rb;j<re;j++) acc = fmaf(g_e[j], h[s_src[j]*33 + c], acc);
    float dn = dinv[n];
    acc += dn * h[n*33 + c];
    float val = fmaxf(dn*acc + gcnb[c], 0.f);
    float inv = bnw[c] / sqrtf(bnv[c] + BN_EPS);
    val = val*inv + (bnb[c] - bnm[c]*inv);
    xp1[n*36 + c] = val;
  }
  int p = t - 231;
  if(p >= 0 && p < 21){
    int np = blockIdx.x*7 + p/3;
    if(np < N_NODES) xp1[np*36 + 33 + (p%3)] = 0.f;
  }
}

// ---------------- GATv2 ----------------
__global__ __launch_bounds__(256) void k_gatlin(const float* __restrict__ xp1, const float* __restrict__ wl,
                                                const float* __restrict__ wr, float* __restrict__ xl,
                                                float* __restrict__ xr){
  int n = blockIdx.x*256 + threadIdx.x;
  if(n >= N_NODES) return;
  float x[36];
  const float4* row = (const float4*)(xp1 + (size_t)n*36);
  #pragma unroll
  for(int q=0;q<9;q++){ float4 v = row[q]; x[q*4]=v.x; x[q*4+1]=v.y; x[q*4+2]=v.z; x[q*4+3]=v.w; }
  for(int j=0;j<132;j++){
    float al = 0.f, ar = 0.f;
    #pragma unroll
    for(int k=0;k<33;k++){
      al = fmaf(x[k], wl[j*33+k], al);
      ar = fmaf(x[k], wr[j*33+k], ar);
    }
    xl[(size_t)n*132 + j] = al;
    xr[(size_t)n*132 + j] = ar;
  }
}

// one block per node; wave 0 = head 0, wave 1 = head 1; lane = channel (c<64, lanes 0/1 also do c=64,65)
__global__ __launch_bounds__(128) void k_gat(const int* __restrict__ rowptr, const int* __restrict__ s_src,
                                             const float* __restrict__ xl, const float* __restrict__ xr,
                                             const float* __restrict__ att, const float* __restrict__ gatb,
                                             float* __restrict__ xp2){
  int n = blockIdx.x;
  int h = threadIdx.x >> 6;
  int lane = threadIdx.x & 63;
  int base = h*66;
  bool ex = (lane < 2);
  float att0 = att[base + lane];
  float att1 = ex ? att[base + 64 + lane] : 0.f;
  size_t nrow = (size_t)n*132;
  float xr0 = xr[nrow + base + lane];
  float xr1 = ex ? xr[nrow + base + 64 + lane] : 0.f;
  // self-loop edge
  float xs0 = xl[nrow + base + lane];
  float xs1 = ex ? xl[nrow + base + 64 + lane] : 0.f;
  float tsum = lrelu(xs0+xr0)*att0 + lrelu(xs1+xr1)*att1;
  float e_self = wsum(tsum);
  float acc0 = xs0, acc1 = xs1, asum = 1.f; // a_self = exp(0) = 1
  int rb = rowptr[n], re = rowptr[n+1];
  for(int j=rb;j<re;j++){
    int s = s_src[j];
    size_t srow = (size_t)s*132;
    float v0 = xl[srow + base + lane];
    float v1 = ex ? xl[srow + base + 64 + lane] : 0.f;
    float tt = lrelu(v0+xr0)*att0 + lrelu(v1+xr1)*att1;
    float e = wsum(tt);
    float a = __expf(e - e_self);
    acc0 = fmaf(a, v0, acc0);
    acc1 = fmaf(a, v1, acc1);
    asum += a;
  }
  float inv = 1.f/asum;
  float o0 = fmaxf(acc0*inv + gatb[base + lane], 0.f);
  xp2[nrow + base + lane] = o0;
  if(ex){
    float o1 = fmaxf(acc1*inv + gatb[base + 64 + lane], 0.f);
    xp2[nrow + base + 64 + lane] = o1;
  }
}

// ---------------- pooling + MLP head ----------------
__global__ __launch_bounds__(256) void k_bounds(const int* __restrict__ batch, int* __restrict__ gstart,
                                                int* __restrict__ gend){
  int n = blockIdx.x*256 + threadIdx.x;
  if(n >= N_NODES) return;
  int b = batch[n];
  atomicMin(&gstart[b], n);
  atomicMax(&gend[b], n+1);
}

__global__ __launch_bounds__(128) void k_pool(const float* __restrict__ xp2, const int* __restrict__ gstart,
                                              const int* __restrict__ gend, float* __restrict__ pooledT){
  int g = blockIdx.x, t = threadIdx.x;
  int s = gstart[g], e = gend[g];
  float a0 = 0.f, a1 = 0.f;
  for(int n=s;n<e;n++){
    a0 += xp2[(size_t)n*132 + t];
    if(t < 4) a1 += xp2[(size_t)n*132 + 128 + t];
  }
  int c = e - s; if(c < 1) c = 1;
  float inv = 1.f/(float)c;
  pooledT[t*64 + g] = a0*inv;
  if(t < 4) pooledT[(128+t)*64 + g] = a1*inv;
}

__global__ __launch_bounds__(256) void k_fc1(const float* __restrict__ pooledT, const float* __restrict__ w,
                                             const float* __restrict__ b, float* __restrict__ h1T){
  int gid = blockIdx.x*256 + threadIdx.x;
  int o = gid >> 6, g = gid & 63;
  float acc = b[o];
  const float* wr = w + o*132;
  for(int k=0;k<132;k++) acc = fmaf(pooledT[k*64+g], wr[k], acc);
  h1T[o*64+g] = fmaxf(acc, 0.f);
}

__global__ __launch_bounds__(256) void k_fc2(const float* __restrict__ h1T, const float* __restrict__ w,
                                             const float* __restrict__ b, float* __restrict__ out){
  int gid = blockIdx.x*256 + threadIdx.x;
  int o = gid >> 6, g = gid & 63;
  float acc = b[o];
  const float* wr = w + o*1024;
  for(int k=0;k<1024;k++) acc = fmaf(h1T[k*64+g], wr[k], acc);
  out[8192 + g*128 + o] = acc;
}

// ---------------- RNA branches ----------------
// S1[b][co][v][k] = sum_{ci: g[b,ci]==v} w[co,ci,k]   (v<5)
__global__ __launch_bounds__(256) void k_s1(const int* __restrict__ g, const float* __restrict__ w,
                                            float* __restrict__ S1){
  __shared__ float S[160];   // 4 co * 5 v * 8 k
  __shared__ int gl[3000];
  int b = blockIdx.x, ch = blockIdx.y, t = threadIdx.x;
  if(t < 160) S[t] = 0.f;
  for(int i=t;i<3000;i+=256) gl[i] = g[b*3000 + i];
  __syncthreads();
  int sub = t & 7, kk = (t>>3)&7, col = t>>6;
  int co = ch*4 + col;
  const float* wrow = w + co*24000 + kk;
  int ci0 = sub*375;
  for(int i=0;i<375;i++){
    int ci = ci0 + i;
    int v = gl[ci];
    atomicAdd(&S[(col*5 + v)*8 + kk], wrow[ci*8]);
  }
  __syncthreads();
  if(t < 160) S1[b*1280 + ch*160 + t] = S[t];
}

// S2: v<65, ci<2998
__global__ __launch_bounds__(256) void k_s2(const int* __restrict__ g, const float* __restrict__ w,
                                            float* __restrict__ S2){
  __shared__ float S[2080];  // 4 co * 65 v * 8 k
  __shared__ int gl[2998];
  int b = blockIdx.x, ch = blockIdx.y, t = threadIdx.x;
  for(int i=t;i<2080;i+=256) S[i] = 0.f;
  for(int i=t;i<2998;i+=256) gl[i] = g[b*2998 + i];
  __syncthreads();
  int sub = t & 7, kk = (t>>3)&7, col = t>>6;
  int co = ch*4 + col;
  const float* wrow = w + co*23984 + kk;
  int ci0 = sub*375;
  for(int i=0;i<375;i++){
    int ci = ci0 + i;
    if(ci < 2998){
      int v = gl[ci];
      atomicAdd(&S[(col*65 + v)*8 + kk], wrow[ci*8]);
    }
  }
  __syncthreads();
  for(int i=t;i<2080;i+=256) S2[(size_t)b*16640 + ch*2080 + i] = S[i];
}

// ysum[b][co*121+l] = 0.5*(conv1+bias1)   (k_y1 writes, k_y2 adds)
__global__ __launch_bounds__(128) void k_y1(const float* __restrict__ S1, const float* __restrict__ emb1,
                                            const float* __restrict__ c1b, float* __restrict__ ysum){
  int b = blockIdx.x, co = blockIdx.y, t = threadIdx.x;
  __shared__ float em[640];
  for(int i=t;i<640;i+=128) em[i] = emb1[i];
  __syncthreads();
  if(t < 121){
    const float* S = S1 + b*1280 + co*40;
    float acc = c1b[co];
    #pragma unroll
    for(int v=0;v<5;v++)
      #pragma unroll
      for(int k=0;k<8;k++) acc = fmaf(S[v*8+k], em[v*128 + t + k], acc);
    ysum[b*3872 + co*121 + t] = 0.5f*acc;
  }
}

__global__ __launch_bounds__(128) void k_y2(const float* __restrict__ S2, const float* __restrict__ emb2,
                                            const float* __restrict__ c2b, float* __restrict__ ysum){
  int b = blockIdx.x, co = blockIdx.y, t = threadIdx.x;
  __shared__ float em[8320];
  for(int i=t;i<8320;i+=128) em[i] = emb2[i];
  __syncthreads();
  if(t < 121){
    const float* S = S2 + (size_t)b*16640 + co*520;
    float acc = c2b[co];
    for(int v=0;v<65;v++){
      #pragma unroll
      for(int k=0;k<8;k++) acc = fmaf(S[v*8+k], em[v*128 + t + k], acc);
    }
    ysum[b*3872 + co*121 + t] += 0.5f*acc;
  }
}

// out[b][o] = sum_j ysum[b][j]*fcw[o][j] + fcb[o]
__global__ __launch_bounds__(256) void k_fcxr(const float* __restrict__ ysum, const float* __restrict__ fcw,
                                              const float* __restrict__ fcb, float* __restrict__ out){
  __shared__ float part[256];
  int b = blockIdx.x, t = threadIdx.x;
  int o = t & 127, half = t >> 7;
  const float* ys = ysum + b*3872 + half*1936;
  const float* wr = fcw + o*3872 + half*1936;
  float acc = 0.f;
  for(int k=0;k<1936;k++) acc = fmaf(ys[k], wr[k], acc);
  part[t] = acc;
  __syncthreads();
  if(t < 128) out[b*128 + t] = part[t] + part[128+t] + fcb[t];
}

extern "C" void kernel_launch(void* const* d_in, const int* in_sizes, int n_in,
                              void* d_out, int out_size, void* d_ws, size_t ws_size,
                              hipStream_t stream){
  const int*   g_rna = (const int*)  d_in[0];
  const int*   l_rna = (const int*)  d_in[1];
  const float* pro_x = (const float*)d_in[2];
  const int*   eidx  = (const int*)  d_in[3];
  const float* pro_w = (const float*)d_in[4];
  const int*   batch = (const int*)  d_in[5];
  const float* emb1  = (const float*)d_in[6];
  const float* emb2  = (const float*)d_in[7];
  const float* c1w   = (const float*)d_in[8];
  const float* c1b   = (const float*)d_in[9];
  const float* c2w   = (const float*)d_in[10];
  const float* c2b   = (const float*)d_in[11];
  const float* fcxw  = (const float*)d_in[12];
  const float* fcxb  = (const float*)d_in[13];
  const float* gcnw  = (const float*)d_in[14];
  const float* gcnb  = (const float*)d_in[15];
  const float* bnm   = (const float*)d_in[16];
  const float* bnv   = (const float*)d_in[17];
  const float* bnw   = (const float*)d_in[18];
  const float* bnb   = (const float*)d_in[19];
  const float* gwl   = (const float*)d_in[20];
  const float* gwr   = (const float*)d_in[21];
  const float* gatt  = (const float*)d_in[22];
  const float* gatb  = (const float*)d_in[23];
  const float* f1w   = (const float*)d_in[24];
  const float* f1b   = (const float*)d_in[25];
  const float* f2w   = (const float*)d_in[26];
  const float* f2b_  = (const float*)d_in[27];
  float* out = (float*)d_out;

  char* ws = (char*)d_ws;
  size_t off = 0;
  auto A = [&](size_t n)->char*{ char* p = ws + off; off = (off + n + 255) & ~(size_t)255; return p; };
  int*   cnt    = (int*)  A((size_t)N_NODES*4);
  int*   rowptr = (int*)  A((size_t)(N_NODES+1)*4);
  int*   fill   = (int*)  A((size_t)N_NODES*4);
  int*   s_src  = (int*)  A((size_t)N_EDGES*4);
  float* s_w    = (float*)A((size_t)N_EDGES*4);
  float* g_e    = (float*)A((size_t)N_EDGES*4);
  float* dinv   = (float*)A((size_t)N_NODES*4);
  float* hbuf   = (float*)A((size_t)N_NODES*33*4);
  float* xp1    = (float*)A((size_t)N_NODES*36*4);
  float* xl     = (float*)A((size_t)N_NODES*132*4);
  float* xr     = (float*)A((size_t)N_NODES*132*4);
  float* xp2    = (float*)A((size_t)N_NODES*132*4);
  int*   gstart = (int*)  A(64*4);
  int*   gend   = (int*)  A(64*4);
  float* pooledT= (float*)A(132*64*4);
  float* h1T    = (float*)A(1024*64*4);
  float* S1     = (float*)A((size_t)64*1280*4);
  float* S2     = (float*)A((size_t)64*16640*4);
  float* ysum   = (float*)A((size_t)64*3872*4);
  (void)ws_size; (void)in_sizes; (void)n_in; (void)out_size;

  // protein GNN pipeline
  k_init   <<<196, 256, 0, stream>>>(cnt, fill, gstart, gend);
  k_hist   <<<3125, 256, 0, stream>>>(eidx, cnt);
  k_scan   <<<1, 1024, 0, stream>>>(cnt, rowptr);
  k_scatter<<<3125, 256, 0, stream>>>(eidx, pro_w, rowptr, fill, s_src, s_w);
  k_deg    <<<196, 256, 0, stream>>>(rowptr, s_w, dinv);
  k_enorm  <<<3125, 256, 0, stream>>>(s_src, s_w, dinv, g_e);
  k_h      <<<196, 256, 0, stream>>>(pro_x, gcnw, hbuf);
  k_gcn    <<<7143, 256, 0, stream>>>(hbuf, rowptr, s_src, g_e, dinv, gcnb, bnm, bnv, bnw, bnb, xp1);
  k_gatlin <<<196, 256, 0, stream>>>(xp1, gwl, gwr, xl, xr);
  k_gat    <<<N_NODES, 128, 0, stream>>>(rowptr, s_src, xl, xr, gatt, gatb, xp2);
  k_bounds <<<196, 256, 0, stream>>>(batch, gstart, gend);
  k_pool   <<<64, 128, 0, stream>>>(xp2, gstart, gend, pooledT);
  k_fc1    <<<256, 256, 0, stream>>>(pooledT, f1w, f1b, h1T);
  k_fc2    <<<32, 256, 0, stream>>>(h1T, f2w, f2b_, out);

  // RNA branches
  k_s1  <<<dim3(64,8), 256, 0, stream>>>(g_rna, c1w, S1);
  k_s2  <<<dim3(64,8), 256, 0, stream>>>(l_rna, c2w, S2);
  k_y1  <<<dim3(64,32), 128, 0, stream>>>(S1, emb1, c1b, ysum);
  k_y2  <<<dim3(64,32), 128, 0, stream>>>(S2, emb2, c2b, ysum);
  k_fcxr<<<64, 256, 0, stream>>>(ysum, fcxw, fcxb, out);
}

// Round 3
// 1562.538 us; speedup vs baseline: 1.1865x; 1.1865x over previous
//
#include <hip/hip_runtime.h>

#define N_NODES 50000
#define N_EDGES 800000
#define LRELU_SLOPE 0.2f
#define BN_EPS 1e-5f

__device__ __forceinline__ float lrelu(float x){ return fmaxf(x,0.f) + LRELU_SLOPE*fminf(x,0.f); }
__device__ __forceinline__ float wsum(float v){
  #pragma unroll
  for(int m=32;m>=1;m>>=1) v += __shfl_xor(v, m, 64);
  return v;
}

// ---------------- CSR build ----------------
__global__ __launch_bounds__(256) void k_init(int* __restrict__ cnt, int* __restrict__ fill,
                                              int* __restrict__ gstart, int* __restrict__ gend){
  int i = blockIdx.x*256 + threadIdx.x;
  if(i < N_NODES){ cnt[i] = 0; fill[i] = 0; }
  if(i < 64){ gstart[i] = N_NODES; gend[i] = 0; }
}

__global__ __launch_bounds__(256) void k_hist(const int* __restrict__ eidx, int* __restrict__ cnt){
  int e = blockIdx.x*256 + threadIdx.x;
  if(e < N_EDGES) atomicAdd(&cnt[eidx[N_EDGES + e]], 1);
}

__global__ __launch_bounds__(1024) void k_scan(const int* __restrict__ cnt, int* __restrict__ rowptr){
  __shared__ int part[1024];
  int t = threadIdx.x;
  const int per = (N_NODES + 1023)/1024; // 49
  int beg = t*per, end = beg+per; if(end > N_NODES) end = N_NODES;
  int s = 0;
  for(int i=beg;i<end;i++) s += cnt[i];
  part[t] = s;
  __syncthreads();
  for(int off=1; off<1024; off<<=1){
    int v = (t>=off) ? part[t-off] : 0;
    __syncthreads();
    part[t] += v;
    __syncthreads();
  }
  int run = (t==0) ? 0 : part[t-1];
  for(int i=beg;i<end;i++){ rowptr[i] = run; run += cnt[i]; }
  if(t==1023) rowptr[N_NODES] = run;
}

__global__ __launch_bounds__(256) void k_scatter(const int* __restrict__ eidx, const float* __restrict__ pw,
                                                 const int* __restrict__ rowptr, int* __restrict__ fill,
                                                 int* __restrict__ s_src, float* __restrict__ s_w){
  int e = blockIdx.x*256 + threadIdx.x;
  if(e < N_EDGES){
    int d = eidx[N_EDGES + e];
    int pos = rowptr[d] + atomicAdd(&fill[d], 1);
    s_src[pos] = eidx[e];
    s_w[pos]   = pw[e];
  }
}

// ---------------- GCN ----------------
__global__ __launch_bounds__(256) void k_deg(const int* __restrict__ rowptr, const float* __restrict__ s_w,
                                             float* __restrict__ dinv){
  int n = blockIdx.x*256 + threadIdx.x;
  if(n >= N_NODES) return;
  int rb = rowptr[n], re = rowptr[n+1];
  float d = 1.f; // self-loop weight
  for(int j=rb;j<re;j++) d += s_w[j];
  dinv[n] = 1.f / sqrtf(d);
}

__global__ __launch_bounds__(256) void k_enorm(const int* __restrict__ s_src, const float* __restrict__ s_w,
                                               const float* __restrict__ dinv, float* __restrict__ g_e){
  int j = blockIdx.x*256 + threadIdx.x;
  if(j < N_EDGES) g_e[j] = dinv[s_src[j]] * s_w[j];
}

__global__ __launch_bounds__(256) void k_h(const float* __restrict__ px, const float* __restrict__ gw,
                                           float* __restrict__ h){
  int n = blockIdx.x*256 + threadIdx.x;
  if(n >= N_NODES) return;
  float x[33];
  #pragma unroll
  for(int k=0;k<33;k++) x[k] = px[n*33+k];
  for(int c=0;c<33;c++){
    float a = 0.f;
    #pragma unroll
    for(int k=0;k<33;k++) a = fmaf(x[k], gw[c*33+k], a);
    h[n*33+c] = a;
  }
}

// xp1 padded to stride 36, fused: agg + gcn_b + relu + BN(eval)
__global__ __launch_bounds__(256) void k_gcn(const float* __restrict__ h, const int* __restrict__ rowptr,
                                             const int* __restrict__ s_src, const float* __restrict__ g_e,
                                             const float* __restrict__ dinv,
                                             const float* __restrict__ gcnb, const float* __restrict__ bnm,
                                             const float* __restrict__ bnv, const float* __restrict__ bnw,
                                             const float* __restrict__ bnb, float* __restrict__ xp1){
  int t = threadIdx.x;
  int nl = t/33, c = t - nl*33;
  int n = blockIdx.x*7 + nl;
  if(nl < 7 && n < N_NODES){
    float acc = 0.f;
    int rb = rowptr[n], re = rowptr[n+1];
    for(int j=rb;j<re;j++) acc = fmaf(g_e[j], h[s_src[j]*33 + c], acc);
    float dn = dinv[n];
    acc += dn * h[n*33 + c];
    float val = fmaxf(dn*acc + gcnb[c], 0.f);
    float inv = bnw[c] / sqrtf(bnv[c] + BN_EPS);
    val = val*inv + (bnb[c] - bnm[c]*inv);
    xp1[n*36 + c] = val;
  }
  int p = t - 231;
  if(p >= 0 && p < 21){
    int np = blockIdx.x*7 + p/3;
    if(np < N_NODES) xp1[np*36 + 33 + (p%3)] = 0.f;
  }
}

// ---------------- GATv2 ----------------
__global__ __launch_bounds__(256) void k_gatlin(const float* __restrict__ xp1, const float* __restrict__ wl,
                                                const float* __restrict__ wr, float* __restrict__ xl,
                                                float* __restrict__ xr){
  int n = blockIdx.x*256 + threadIdx.x;
  if(n >= N_NODES) return;
  float x[36];
  const float4* row = (const float4*)(xp1 + (size_t)n*36);
  #pragma unroll
  for(int q=0;q<9;q++){ float4 v = row[q]; x[q*4]=v.x; x[q*4+1]=v.y; x[q*4+2]=v.z; x[q*4+3]=v.w; }
  for(int j=0;j<132;j++){
    float al = 0.f, ar = 0.f;
    #pragma unroll
    for(int k=0;k<33;k++){
      al = fmaf(x[k], wl[j*33+k], al);
      ar = fmaf(x[k], wr[j*33+k], ar);
    }
    xl[(size_t)n*132 + j] = al;
    xr[(size_t)n*132 + j] = ar;
  }
}

// one block per node; wave 0 = head 0, wave 1 = head 1; lane = channel (c<64, lanes 0/1 also do c=64,65)
__global__ __launch_bounds__(128) void k_gat(const int* __restrict__ rowptr, const int* __restrict__ s_src,
                                             const float* __restrict__ xl, const float* __restrict__ xr,
                                             const float* __restrict__ att, const float* __restrict__ gatb,
                                             float* __restrict__ xp2){
  int n = blockIdx.x;
  int h = threadIdx.x >> 6;
  int lane = threadIdx.x & 63;
  int base = h*66;
  bool ex = (lane < 2);
  float att0 = att[base + lane];
  float att1 = ex ? att[base + 64 + lane] : 0.f;
  size_t nrow = (size_t)n*132;
  float xr0 = xr[nrow + base + lane];
  float xr1 = ex ? xr[nrow + base + 64 + lane] : 0.f;
  // self-loop edge
  float xs0 = xl[nrow + base + lane];
  float xs1 = ex ? xl[nrow + base + 64 + lane] : 0.f;
  float tsum = lrelu(xs0+xr0)*att0 + lrelu(xs1+xr1)*att1;
  float e_self = wsum(tsum);
  float acc0 = xs0, acc1 = xs1, asum = 1.f; // a_self = exp(0) = 1
  int rb = rowptr[n], re = rowptr[n+1];
  for(int j=rb;j<re;j++){
    int s = s_src[j];
    size_t srow = (size_t)s*132;
    float v0 = xl[srow + base + lane];
    float v1 = ex ? xl[srow + base + 64 + lane] : 0.f;
    float tt = lrelu(v0+xr0)*att0 + lrelu(v1+xr1)*att1;
    float e = wsum(tt);
    float a = __expf(e - e_self);
    acc0 = fmaf(a, v0, acc0);
    acc1 = fmaf(a, v1, acc1);
    asum += a;
  }
  float inv = 1.f/asum;
  float o0 = fmaxf(acc0*inv + gatb[base + lane], 0.f);
  xp2[nrow + base + lane] = o0;
  if(ex){
    float o1 = fmaxf(acc1*inv + gatb[base + 64 + lane], 0.f);
    xp2[nrow + base + 64 + lane] = o1;
  }
}

// ---------------- pooling + MLP head ----------------
// pro_batch is SORTED -> boundary detection, zero atomics (was 100K atomics @ 64 addrs = 290us)
__global__ __launch_bounds__(256) void k_bounds(const int* __restrict__ batch, int* __restrict__ gstart,
                                                int* __restrict__ gend){
  int n = blockIdx.x*256 + threadIdx.x;
  if(n >= N_NODES) return;
  int b = batch[n];
  if(n == 0) gstart[b] = 0;
  else {
    int p = batch[n-1];
    if(p != b){ gstart[b] = n; gend[p] = n; }
  }
  if(n == N_NODES-1) gend[b] = N_NODES;
}

__global__ __launch_bounds__(128) void k_pool(const float* __restrict__ xp2, const int* __restrict__ gstart,
                                              const int* __restrict__ gend, float* __restrict__ pooledT){
  int g = blockIdx.x, t = threadIdx.x;
  int s = gstart[g], e = gend[g];
  float a0 = 0.f, a1 = 0.f;
  for(int n=s;n<e;n++){
    a0 += xp2[(size_t)n*132 + t];
    if(t < 4) a1 += xp2[(size_t)n*132 + 128 + t];
  }
  int c = e - s; if(c < 1) c = 1;
  float inv = 1.f/(float)c;
  pooledT[t*64 + g] = a0*inv;
  if(t < 4) pooledT[(128+t)*64 + g] = a1*inv;
}

__global__ __launch_bounds__(256) void k_fc1(const float* __restrict__ pooledT, const float* __restrict__ w,
                                             const float* __restrict__ b, float* __restrict__ h1T){
  int gid = blockIdx.x*256 + threadIdx.x;
  int o = gid >> 6, g = gid & 63;
  float acc = b[o];
  const float* wr = w + o*132;
  for(int k=0;k<132;k++) acc = fmaf(pooledT[k*64+g], wr[k], acc);
  h1T[o*64+g] = fmaxf(acc, 0.f);
}

__global__ __launch_bounds__(256) void k_fc2(const float* __restrict__ h1T, const float* __restrict__ w,
                                             const float* __restrict__ b, float* __restrict__ out){
  int gid = blockIdx.x*256 + threadIdx.x;
  int o = gid >> 6, g = gid & 63;
  float acc = b[o];
  const float* wr = w + o*1024;
  for(int k=0;k<1024;k++) acc = fmaf(h1T[k*64+g], wr[k], acc);
  out[8192 + g*128 + o] = acc;
}

// ---------------- RNA branches ----------------
// S1[b][co][v][k] = sum_{ci: g[b,ci]==v} w[co,ci,k]   (v<5)
__global__ __launch_bounds__(256) void k_s1(const int* __restrict__ g, const float* __restrict__ w,
                                            float* __restrict__ S1){
  __shared__ float S[160];   // 4 co * 5 v * 8 k
  __shared__ int gl[3000];
  int b = blockIdx.x, ch = blockIdx.y, t = threadIdx.x;
  if(t < 160) S[t] = 0.f;
  for(int i=t;i<3000;i+=256) gl[i] = g[b*3000 + i];
  __syncthreads();
  int sub = t & 7, kk = (t>>3)&7, col = t>>6;
  int co = ch*4 + col;
  const float* wrow = w + co*24000 + kk;
  int ci0 = sub*375;
  for(int i=0;i<375;i++){
    int ci = ci0 + i;
    int v = gl[ci];
    atomicAdd(&S[(col*5 + v)*8 + kk], wrow[ci*8]);
  }
  __syncthreads();
  if(t < 160) S1[b*1280 + ch*160 + t] = S[t];
}

// S2: v<65, ci<2998
__global__ __launch_bounds__(256) void k_s2(const int* __restrict__ g, const float* __restrict__ w,
                                            float* __restrict__ S2){
  __shared__ float S[2080];  // 4 co * 65 v * 8 k
  __shared__ int gl[2998];
  int b = blockIdx.x, ch = blockIdx.y, t = threadIdx.x;
  for(int i=t;i<2080;i+=256) S[i] = 0.f;
  for(int i=t;i<2998;i+=256) gl[i] = g[b*2998 + i];
  __syncthreads();
  int sub = t & 7, kk = (t>>3)&7, col = t>>6;
  int co = ch*4 + col;
  const float* wrow = w + co*23984 + kk;
  int ci0 = sub*375;
  for(int i=0;i<375;i++){
    int ci = ci0 + i;
    if(ci < 2998){
      int v = gl[ci];
      atomicAdd(&S[(col*65 + v)*8 + kk], wrow[ci*8]);
    }
  }
  __syncthreads();
  for(int i=t;i<2080;i+=256) S2[(size_t)b*16640 + ch*2080 + i] = S[i];
}

// ysum[b][co*121+l] = 0.5*(conv1+bias1)   (k_y1 writes, k_y2 adds)
__global__ __launch_bounds__(128) void k_y1(const float* __restrict__ S1, const float* __restrict__ emb1,
                                            const float* __restrict__ c1b, float* __restrict__ ysum){
  int b = blockIdx.x, co = blockIdx.y, t = threadIdx.x;
  __shared__ float em[640];
  for(int i=t;i<640;i+=128) em[i] = emb1[i];
  __syncthreads();
  if(t < 121){
    const float* S = S1 + b*1280 + co*40;
    float acc = c1b[co];
    #pragma unroll
    for(int v=0;v<5;v++)
      #pragma unroll
      for(int k=0;k<8;k++) acc = fmaf(S[v*8+k], em[v*128 + t + k], acc);
    ysum[b*3872 + co*121 + t] = 0.5f*acc;
  }
}

__global__ __launch_bounds__(128) void k_y2(const float* __restrict__ S2, const float* __restrict__ emb2,
                                            const float* __restrict__ c2b, float* __restrict__ ysum){
  int b = blockIdx.x, co = blockIdx.y, t = threadIdx.x;
  __shared__ float em[8320];
  for(int i=t;i<8320;i+=128) em[i] = emb2[i];
  __syncthreads();
  if(t < 121){
    const float* S = S2 + (size_t)b*16640 + co*520;
    float acc = c2b[co];
    for(int v=0;v<65;v++){
      #pragma unroll
      for(int k=0;k<8;k++) acc = fmaf(S[v*8+k], em[v*128 + t + k], acc);
    }
    ysum[b*3872 + co*121 + t] += 0.5f*acc;
  }
}

// out[b][o] = sum_j ysum[b][j]*fcw[o][j] + fcb[o]
__global__ __launch_bounds__(256) void k_fcxr(const float* __restrict__ ysum, const float* __restrict__ fcw,
                                              const float* __restrict__ fcb, float* __restrict__ out){
  __shared__ float part[256];
  int b = blockIdx.x, t = threadIdx.x;
  int o = t & 127, half = t >> 7;
  const float* ys = ysum + b*3872 + half*1936;
  const float* wr = fcw + o*3872 + half*1936;
  float acc = 0.f;
  for(int k=0;k<1936;k++) acc = fmaf(ys[k], wr[k], acc);
  part[t] = acc;
  __syncthreads();
  if(t < 128) out[b*128 + t] = part[t] + part[128+t] + fcb[t];
}

extern "C" void kernel_launch(void* const* d_in, const int* in_sizes, int n_in,
                              void* d_out, int out_size, void* d_ws, size_t ws_size,
                              hipStream_t stream){
  const int*   g_rna = (const int*)  d_in[0];
  const int*   l_rna = (const int*)  d_in[1];
  const float* pro_x = (const float*)d_in[2];
  const int*   eidx  = (const int*)  d_in[3];
  const float* pro_w = (const float*)d_in[4];
  const int*   batch = (const int*)  d_in[5];
  const float* emb1  = (const float*)d_in[6];
  const float* emb2  = (const float*)d_in[7];
  const float* c1w   = (const float*)d_in[8];
  const float* c1b   = (const float*)d_in[9];
  const float* c2w   = (const float*)d_in[10];
  const float* c2b   = (const float*)d_in[11];
  const float* fcxw  = (const float*)d_in[12];
  const float* fcxb  = (const float*)d_in[13];
  const float* gcnw  = (const float*)d_in[14];
  const float* gcnb  = (const float*)d_in[15];
  const float* bnm   = (const float*)d_in[16];
  const float* bnv   = (const float*)d_in[17];
  const float* bnw   = (const float*)d_in[18];
  const float* bnb   = (const float*)d_in[19];
  const float* gwl   = (const float*)d_in[20];
  const float* gwr   = (const float*)d_in[21];
  const float* gatt  = (const float*)d_in[22];
  const float* gatb  = (const float*)d_in[23];
  const float* f1w   = (const float*)d_in[24];
  const float* f1b   = (const float*)d_in[25];
  const float* f2w   = (const float*)d_in[26];
  const float* f2b_  = (const float*)d_in[27];
  float* out = (float*)d_out;

  char* ws = (char*)d_ws;
  size_t off = 0;
  auto A = [&](size_t n)->char*{ char* p = ws + off; off = (off + n + 255) & ~(size_t)255; return p; };
  int*   cnt    = (int*)  A((size_t)N_NODES*4);
  int*   rowptr = (int*)  A((size_t)(N_NODES+1)*4);
  int*   fill   = (int*)  A((size_t)N_NODES*4);
  int*   s_src  = (int*)  A((size_t)N_EDGES*4);
  float* s_w    = (float*)A((size_t)N_EDGES*4);
  float* g_e    = (float*)A((size_t)N_EDGES*4);
  float* dinv   = (float*)A((size_t)N_NODES*4);
  float* hbuf   = (float*)A((size_t)N_NODES*33*4);
  float* xp1    = (float*)A((size_t)N_NODES*36*4);
  float* xl     = (float*)A((size_t)N_NODES*132*4);
  float* xr     = (float*)A((size_t)N_NODES*132*4);
  float* xp2    = (float*)A((size_t)N_NODES*132*4);
  int*   gstart = (int*)  A(64*4);
  int*   gend   = (int*)  A(64*4);
  float* pooledT= (float*)A(132*64*4);
  float* h1T    = (float*)A(1024*64*4);
  float* S1     = (float*)A((size_t)64*1280*4);
  float* S2     = (float*)A((size_t)64*16640*4);
  float* ysum   = (float*)A((size_t)64*3872*4);
  (void)ws_size; (void)in_sizes; (void)n_in; (void)out_size;

  // protein GNN pipeline
  k_init   <<<196, 256, 0, stream>>>(cnt, fill, gstart, gend);
  k_hist   <<<3125, 256, 0, stream>>>(eidx, cnt);
  k_scan   <<<1, 1024, 0, stream>>>(cnt, rowptr);
  k_scatter<<<3125, 256, 0, stream>>>(eidx, pro_w, rowptr, fill, s_src, s_w);
  k_deg    <<<196, 256, 0, stream>>>(rowptr, s_w, dinv);
  k_enorm  <<<3125, 256, 0, stream>>>(s_src, s_w, dinv, g_e);
  k_h      <<<196, 256, 0, stream>>>(pro_x, gcnw, hbuf);
  k_gcn    <<<7143, 256, 0, stream>>>(hbuf, rowptr, s_src, g_e, dinv, gcnb, bnm, bnv, bnw, bnb, xp1);
  k_gatlin <<<196, 256, 0, stream>>>(xp1, gwl, gwr, xl, xr);
  k_gat    <<<N_NODES, 128, 0, stream>>>(rowptr, s_src, xl, xr, gatt, gatb, xp2);
  k_bounds <<<196, 256, 0, stream>>>(batch, gstart, gend);
  k_pool   <<<64, 128, 0, stream>>>(xp2, gstart, gend, pooledT);
  k_fc1    <<<256, 256, 0, stream>>>(pooledT, f1w, f1b, h1T);
  k_fc2    <<<32, 256, 0, stream>>>(h1T, f2w, f2b_, out);

  // RNA branches
  k_s1  <<<dim3(64,8), 256, 0, stream>>>(g_rna, c1w, S1);
  k_s2  <<<dim3(64,8), 256, 0, stream>>>(l_rna, c2w, S2);
  k_y1  <<<dim3(64,32), 128, 0, stream>>>(S1, emb1, c1b, ysum);
  k_y2  <<<dim3(64,32), 128, 0, stream>>>(S2, emb2, c2b, ysum);
  k_fcxr<<<64, 256, 0, stream>>>(ysum, fcxw, fcxb, out);
}

// Round 4
// 1208.521 us; speedup vs baseline: 1.5340x; 1.2929x over previous
//
#include <hip/hip_runtime.h>

#define N_NODES 50000
#define N_EDGES 800000
#define LRELU_SLOPE 0.2f
#define BN_EPS 1e-5f

__device__ __forceinline__ float lrelu(float x){ return fmaxf(x,0.f) + LRELU_SLOPE*fminf(x,0.f); }
__device__ __forceinline__ float wsum(float v){
  #pragma unroll
  for(int m=32;m>=1;m>>=1) v += __shfl_xor(v, m, 64);
  return v;
}

// ---------------- CSR build ----------------
__global__ __launch_bounds__(256) void k_init(int* __restrict__ cnt, int* __restrict__ fill,
                                              int* __restrict__ gstart, int* __restrict__ gend){
  int i = blockIdx.x*256 + threadIdx.x;
  if(i < N_NODES){ cnt[i] = 0; fill[i] = 0; }
  if(i < 64){ gstart[i] = N_NODES; gend[i] = 0; }
}

__global__ __launch_bounds__(256) void k_hist(const int* __restrict__ eidx, int* __restrict__ cnt){
  int e = blockIdx.x*256 + threadIdx.x;
  if(e < N_EDGES) atomicAdd(&cnt[eidx[N_EDGES + e]], 1);
}

__global__ __launch_bounds__(1024) void k_scan(const int* __restrict__ cnt, int* __restrict__ rowptr){
  __shared__ int part[1024];
  int t = threadIdx.x;
  const int per = (N_NODES + 1023)/1024; // 49
  int beg = t*per, end = beg+per; if(end > N_NODES) end = N_NODES;
  int s = 0;
  for(int i=beg;i<end;i++) s += cnt[i];
  part[t] = s;
  __syncthreads();
  for(int off=1; off<1024; off<<=1){
    int v = (t>=off) ? part[t-off] : 0;
    __syncthreads();
    part[t] += v;
    __syncthreads();
  }
  int run = (t==0) ? 0 : part[t-1];
  for(int i=beg;i<end;i++){ rowptr[i] = run; run += cnt[i]; }
  if(t==1023) rowptr[N_NODES] = run;
}

__global__ __launch_bounds__(256) void k_scatter(const int* __restrict__ eidx, const float* __restrict__ pw,
                                                 const int* __restrict__ rowptr, int* __restrict__ fill,
                                                 int* __restrict__ s_src, float* __restrict__ s_w){
  int e = blockIdx.x*256 + threadIdx.x;
  if(e < N_EDGES){
    int d = eidx[N_EDGES + e];
    int pos = rowptr[d] + atomicAdd(&fill[d], 1);
    s_src[pos] = eidx[e];
    s_w[pos]   = pw[e];
  }
}

// ---------------- GCN ----------------
__global__ __launch_bounds__(256) void k_deg(const int* __restrict__ rowptr, const float* __restrict__ s_w,
                                             float* __restrict__ dinv){
  int n = blockIdx.x*256 + threadIdx.x;
  if(n >= N_NODES) return;
  int rb = rowptr[n], re = rowptr[n+1];
  float d = 1.f; // self-loop weight
  for(int j=rb;j<re;j++) d += s_w[j];
  dinv[n] = 1.f / sqrtf(d);
}

__global__ __launch_bounds__(256) void k_enorm(const int* __restrict__ s_src, const float* __restrict__ s_w,
                                               const float* __restrict__ dinv, float* __restrict__ g_e){
  int j = blockIdx.x*256 + threadIdx.x;
  if(j < N_EDGES) g_e[j] = dinv[s_src[j]] * s_w[j];
}

__global__ __launch_bounds__(256) void k_h(const float* __restrict__ px, const float* __restrict__ gw,
                                           float* __restrict__ h){
  int n = blockIdx.x*256 + threadIdx.x;
  if(n >= N_NODES) return;
  float x[33];
  #pragma unroll
  for(int k=0;k<33;k++) x[k] = px[n*33+k];
  for(int c=0;c<33;c++){
    float a = 0.f;
    #pragma unroll
    for(int k=0;k<33;k++) a = fmaf(x[k], gw[c*33+k], a);
    h[n*33+c] = a;
  }
}

// xp1 padded to stride 36, fused: agg + gcn_b + relu + BN(eval)
__global__ __launch_bounds__(256) void k_gcn(const float* __restrict__ h, const int* __restrict__ rowptr,
                                             const int* __restrict__ s_src, const float* __restrict__ g_e,
                                             const float* __restrict__ dinv,
                                             const float* __restrict__ gcnb, const float* __restrict__ bnm,
                                             const float* __restrict__ bnv, const float* __restrict__ bnw,
                                             const float* __restrict__ bnb, float* __restrict__ xp1){
  int t = threadIdx.x;
  int nl = t/33, c = t - nl*33;
  int n = blockIdx.x*7 + nl;
  if(nl < 7 && n < N_NODES){
    float acc = 0.f;
    int rb = rowptr[n], re = rowptr[n+1];
    for(int j=rb;j<re;j++) acc = fmaf(g_e[j], h[s_src[j]*33 + c], acc);
    float dn = dinv[n];
    acc += dn * h[n*33 + c];
    float val = fmaxf(dn*acc + gcnb[c], 0.f);
    float inv = bnw[c] / sqrtf(bnv[c] + BN_EPS);
    val = val*inv + (bnb[c] - bnm[c]*inv);
    xp1[n*36 + c] = val;
  }
  int p = t - 231;
  if(p >= 0 && p < 21){
    int np = blockIdx.x*7 + p/3;
    if(np < N_NODES) xp1[np*36 + 33 + (p%3)] = 0.f;
  }
}

// ---------------- GATv2 ----------------
__global__ __launch_bounds__(256) void k_gatlin(const float* __restrict__ xp1, const float* __restrict__ wl,
                                                const float* __restrict__ wr, float* __restrict__ xl,
                                                float* __restrict__ xr){
  int n = blockIdx.x*256 + threadIdx.x;
  if(n >= N_NODES) return;
  float x[36];
  const float4* row = (const float4*)(xp1 + (size_t)n*36);
  #pragma unroll
  for(int q=0;q<9;q++){ float4 v = row[q]; x[q*4]=v.x; x[q*4+1]=v.y; x[q*4+2]=v.z; x[q*4+3]=v.w; }
  for(int j=0;j<132;j++){
    float al = 0.f, ar = 0.f;
    #pragma unroll
    for(int k=0;k<33;k++){
      al = fmaf(x[k], wl[j*33+k], al);
      ar = fmaf(x[k], wr[j*33+k], ar);
    }
    xl[(size_t)n*132 + j] = al;
    xr[(size_t)n*132 + j] = ar;
  }
}

// one block per node; wave 0 = head 0, wave 1 = head 1; lane = channel (c<64, lanes 0/1 also do c=64,65)
__global__ __launch_bounds__(128) void k_gat(const int* __restrict__ rowptr, const int* __restrict__ s_src,
                                             const float* __restrict__ xl, const float* __restrict__ xr,
                                             const float* __restrict__ att, const float* __restrict__ gatb,
                                             float* __restrict__ xp2){
  int n = blockIdx.x;
  int h = threadIdx.x >> 6;
  int lane = threadIdx.x & 63;
  int base = h*66;
  bool ex = (lane < 2);
  float att0 = att[base + lane];
  float att1 = ex ? att[base + 64 + lane] : 0.f;
  size_t nrow = (size_t)n*132;
  float xr0 = xr[nrow + base + lane];
  float xr1 = ex ? xr[nrow + base + 64 + lane] : 0.f;
  // self-loop edge
  float xs0 = xl[nrow + base + lane];
  float xs1 = ex ? xl[nrow + base + 64 + lane] : 0.f;
  float tsum = lrelu(xs0+xr0)*att0 + lrelu(xs1+xr1)*att1;
  float e_self = wsum(tsum);
  float acc0 = xs0, acc1 = xs1, asum = 1.f; // a_self = exp(0) = 1
  int rb = rowptr[n], re = rowptr[n+1];
  for(int j=rb;j<re;j++){
    int s = s_src[j];
    size_t srow = (size_t)s*132;
    float v0 = xl[srow + base + lane];
    float v1 = ex ? xl[srow + base + 64 + lane] : 0.f;
    float tt = lrelu(v0+xr0)*att0 + lrelu(v1+xr1)*att1;
    float e = wsum(tt);
    float a = __expf(e - e_self);
    acc0 = fmaf(a, v0, acc0);
    acc1 = fmaf(a, v1, acc1);
    asum += a;
  }
  float inv = 1.f/asum;
  float o0 = fmaxf(acc0*inv + gatb[base + lane], 0.f);
  xp2[nrow + base + lane] = o0;
  if(ex){
    float o1 = fmaxf(acc1*inv + gatb[base + 64 + lane], 0.f);
    xp2[nrow + base + 64 + lane] = o1;
  }
}

// ---------------- pooling + MLP head ----------------
// pro_batch is SORTED -> boundary detection, zero atomics
__global__ __launch_bounds__(256) void k_bounds(const int* __restrict__ batch, int* __restrict__ gstart,
                                                int* __restrict__ gend){
  int n = blockIdx.x*256 + threadIdx.x;
  if(n >= N_NODES) return;
  int b = batch[n];
  if(n == 0) gstart[b] = 0;
  else {
    int p = batch[n-1];
    if(p != b){ gstart[b] = n; gend[p] = n; }
  }
  if(n == N_NODES-1) gend[b] = N_NODES;
}

__global__ __launch_bounds__(128) void k_pool(const float* __restrict__ xp2, const int* __restrict__ gstart,
                                              const int* __restrict__ gend, float* __restrict__ pooledT){
  int g = blockIdx.x, t = threadIdx.x;
  int s = gstart[g], e = gend[g];
  float a0 = 0.f, a1 = 0.f;
  for(int n=s;n<e;n++){
    a0 += xp2[(size_t)n*132 + t];
    if(t < 4) a1 += xp2[(size_t)n*132 + 128 + t];
  }
  int c = e - s; if(c < 1) c = 1;
  float inv = 1.f/(float)c;
  pooledT[t*64 + g] = a0*inv;
  if(t < 4) pooledT[(128+t)*64 + g] = a1*inv;
}

__global__ __launch_bounds__(256) void k_fc1(const float* __restrict__ pooledT, const float* __restrict__ w,
                                             const float* __restrict__ b, float* __restrict__ h1T){
  int gid = blockIdx.x*256 + threadIdx.x;
  int o = gid >> 6, g = gid & 63;
  float acc = b[o];
  const float* wr = w + o*132;
  for(int k=0;k<132;k++) acc = fmaf(pooledT[k*64+g], wr[k], acc);
  h1T[o*64+g] = fmaxf(acc, 0.f);
}

__global__ __launch_bounds__(256) void k_fc2(const float* __restrict__ h1T, const float* __restrict__ w,
                                             const float* __restrict__ b, float* __restrict__ out){
  int gid = blockIdx.x*256 + threadIdx.x;
  int o = gid >> 6, g = gid & 63;
  float acc = b[o];
  const float* wr = w + o*1024;
  for(int k=0;k<1024;k++) acc = fmaf(h1T[k*64+g], wr[k], acc);
  out[8192 + g*128 + o] = acc;
}

// ---------------- RNA branches ----------------
// Coalesced, atomic-free bucketed segment-sum.
// Block = (b, co), 64 threads. Octet o = lane>>3 shares one ci (one v); kk = lane&7.
// LDS privatized per octet -> no same-address RMW within any wave instruction.
// S1[b][co][v][k] = sum_{ci: g[b,ci]==v} w[co,ci,k]   (v<5)
__global__ __launch_bounds__(64) void k_s1(const int* __restrict__ g, const float* __restrict__ w,
                                           float* __restrict__ S1){
  __shared__ float Sp[320]; // [o=8][v=5][k=8]
  int b = blockIdx.x, co = blockIdx.y, lane = threadIdx.x;
  for(int i=lane;i<320;i+=64) Sp[i]=0.f;
  __syncthreads();
  const float* wrow = w + co*24000;
  const int*   grow = g + b*3000;
  int ob = (lane>>3)*40, kk = lane&7;
  for(int iter=0; iter<375; ++iter){
    int idx = iter*64 + lane;
    float wv = wrow[idx];          // fully coalesced
    int v = grow[idx>>3];          // octet-broadcast, L1-hot
    Sp[ob + v*8 + kk] += wv;       // race-free (octet-private)
  }
  __syncthreads();
  if(lane < 40){
    float s = 0.f;
    #pragma unroll
    for(int o=0;o<8;o++) s += Sp[o*40 + lane];
    S1[b*1280 + co*40 + lane] = s;
  }
}

// S2: v<65, ci<2998 (row = 23984 elements)
__global__ __launch_bounds__(64) void k_s2(const int* __restrict__ g, const float* __restrict__ w,
                                           float* __restrict__ S2){
  __shared__ float Sp[4160]; // [o=8][v=65][k=8] = 16.6 KB
  int b = blockIdx.x, co = blockIdx.y, lane = threadIdx.x;
  for(int i=lane;i<4160;i+=64) Sp[i]=0.f;
  __syncthreads();
  const float* wrow = w + co*23984;
  const int*   grow = g + b*2998;
  int ob = (lane>>3)*520, kk = lane&7;
  for(int iter=0; iter<375; ++iter){
    int idx = iter*64 + lane;
    if(idx < 23984){
      float wv = wrow[idx];
      int v = grow[idx>>3];
      Sp[ob + v*8 + kk] += wv;
    }
  }
  __syncthreads();
  for(int r=0;r<9;r++){
    int j = r*64 + lane;
    if(j < 520){
      float s = 0.f;
      #pragma unroll
      for(int o=0;o<8;o++) s += Sp[o*520 + j];
      S2[(size_t)b*16640 + co*520 + j] = s;
    }
  }
}

// ysum[b][co*121+l] = 0.5*(conv1+bias1)   (k_y1 writes, k_y2 adds)
__global__ __launch_bounds__(128) void k_y1(const float* __restrict__ S1, const float* __restrict__ emb1,
                                            const float* __restrict__ c1b, float* __restrict__ ysum){
  int b = blockIdx.x, co = blockIdx.y, t = threadIdx.x;
  __shared__ float em[640];
  for(int i=t;i<640;i+=128) em[i] = emb1[i];
  __syncthreads();
  if(t < 121){
    const float* S = S1 + b*1280 + co*40;
    float acc = c1b[co];
    #pragma unroll
    for(int v=0;v<5;v++)
      #pragma unroll
      for(int k=0;k<8;k++) acc = fmaf(S[v*8+k], em[v*128 + t + k], acc);
    ysum[b*3872 + co*121 + t] = 0.5f*acc;
  }
}

__global__ __launch_bounds__(128) void k_y2(const float* __restrict__ S2, const float* __restrict__ emb2,
                                            const float* __restrict__ c2b, float* __restrict__ ysum){
  int b = blockIdx.x, co = blockIdx.y, t = threadIdx.x;
  __shared__ float em[8320];
  for(int i=t;i<8320;i+=128) em[i] = emb2[i];
  __syncthreads();
  if(t < 121){
    const float* S = S2 + (size_t)b*16640 + co*520;
    float acc = c2b[co];
    for(int v=0;v<65;v++){
      #pragma unroll
      for(int k=0;k<8;k++) acc = fmaf(S[v*8+k], em[v*128 + t + k], acc);
    }
    ysum[b*3872 + co*121 + t] += 0.5f*acc;
  }
}

// out[b][o] = sum_j ysum[b][j]*fcw[o][j] + fcb[o]  (float4 streams)
__global__ __launch_bounds__(256) void k_fcxr(const float* __restrict__ ysum, const float* __restrict__ fcw,
                                              const float* __restrict__ fcb, float* __restrict__ out){
  __shared__ float part[256];
  int b = blockIdx.x, t = threadIdx.x;
  int o = t & 127, half = t >> 7;
  const float4* ys = (const float4*)(ysum + b*3872 + half*1936);
  const float4* wr = (const float4*)(fcw + o*3872 + half*1936);
  float acc = 0.f;
  for(int k=0;k<484;k++){
    float4 y = ys[k], q = wr[k];
    acc += y.x*q.x + y.y*q.y + y.z*q.z + y.w*q.w;
  }
  part[t] = acc;
  __syncthreads();
  if(t < 128) out[b*128 + t] = part[t] + part[128+t] + fcb[t];
}

extern "C" void kernel_launch(void* const* d_in, const int* in_sizes, int n_in,
                              void* d_out, int out_size, void* d_ws, size_t ws_size,
                              hipStream_t stream){
  const int*   g_rna = (const int*)  d_in[0];
  const int*   l_rna = (const int*)  d_in[1];
  const float* pro_x = (const float*)d_in[2];
  const int*   eidx  = (const int*)  d_in[3];
  const float* pro_w = (const float*)d_in[4];
  const int*   batch = (const int*)  d_in[5];
  const float* emb1  = (const float*)d_in[6];
  const float* emb2  = (const float*)d_in[7];
  const float* c1w   = (const float*)d_in[8];
  const float* c1b   = (const float*)d_in[9];
  const float* c2w   = (const float*)d_in[10];
  const float* c2b   = (const float*)d_in[11];
  const float* fcxw  = (const float*)d_in[12];
  const float* fcxb  = (const float*)d_in[13];
  const float* gcnw  = (const float*)d_in[14];
  const float* gcnb  = (const float*)d_in[15];
  const float* bnm   = (const float*)d_in[16];
  const float* bnv   = (const float*)d_in[17];
  const float* bnw   = (const float*)d_in[18];
  const float* bnb   = (const float*)d_in[19];
  const float* gwl   = (const float*)d_in[20];
  const float* gwr   = (const float*)d_in[21];
  const float* gatt  = (const float*)d_in[22];
  const float* gatb  = (const float*)d_in[23];
  const float* f1w   = (const float*)d_in[24];
  const float* f1b   = (const float*)d_in[25];
  const float* f2w   = (const float*)d_in[26];
  const float* f2b_  = (const float*)d_in[27];
  float* out = (float*)d_out;

  char* ws = (char*)d_ws;
  size_t off = 0;
  auto A = [&](size_t n)->char*{ char* p = ws + off; off = (off + n + 255) & ~(size_t)255; return p; };
  int*   cnt    = (int*)  A((size_t)N_NODES*4);
  int*   rowptr = (int*)  A((size_t)(N_NODES+1)*4);
  int*   fill   = (int*)  A((size_t)N_NODES*4);
  int*   s_src  = (int*)  A((size_t)N_EDGES*4);
  float* s_w    = (float*)A((size_t)N_EDGES*4);
  float* g_e    = (float*)A((size_t)N_EDGES*4);
  float* dinv   = (float*)A((size_t)N_NODES*4);
  float* hbuf   = (float*)A((size_t)N_NODES*33*4);
  float* xp1    = (float*)A((size_t)N_NODES*36*4);
  float* xl     = (float*)A((size_t)N_NODES*132*4);
  float* xr     = (float*)A((size_t)N_NODES*132*4);
  float* xp2    = (float*)A((size_t)N_NODES*132*4);
  int*   gstart = (int*)  A(64*4);
  int*   gend   = (int*)  A(64*4);
  float* pooledT= (float*)A(132*64*4);
  float* h1T    = (float*)A(1024*64*4);
  float* S1     = (float*)A((size_t)64*1280*4);
  float* S2     = (float*)A((size_t)64*16640*4);
  float* ysum   = (float*)A((size_t)64*3872*4);
  (void)ws_size; (void)in_sizes; (void)n_in; (void)out_size;

  // protein GNN pipeline
  k_init   <<<196, 256, 0, stream>>>(cnt, fill, gstart, gend);
  k_hist   <<<3125, 256, 0, stream>>>(eidx, cnt);
  k_scan   <<<1, 1024, 0, stream>>>(cnt, rowptr);
  k_scatter<<<3125, 256, 0, stream>>>(eidx, pro_w, rowptr, fill, s_src, s_w);
  k_deg    <<<196, 256, 0, stream>>>(rowptr, s_w, dinv);
  k_enorm  <<<3125, 256, 0, stream>>>(s_src, s_w, dinv, g_e);
  k_h      <<<196, 256, 0, stream>>>(pro_x, gcnw, hbuf);
  k_gcn    <<<7143, 256, 0, stream>>>(hbuf, rowptr, s_src, g_e, dinv, gcnb, bnm, bnv, bnw, bnb, xp1);
  k_gatlin <<<196, 256, 0, stream>>>(xp1, gwl, gwr, xl, xr);
  k_gat    <<<N_NODES, 128, 0, stream>>>(rowptr, s_src, xl, xr, gatt, gatb, xp2);
  k_bounds <<<196, 256, 0, stream>>>(batch, gstart, gend);
  k_pool   <<<64, 128, 0, stream>>>(xp2, gstart, gend, pooledT);
  k_fc1    <<<256, 256, 0, stream>>>(pooledT, f1w, f1b, h1T);
  k_fc2    <<<32, 256, 0, stream>>>(h1T, f2w, f2b_, out);

  // RNA branches
  k_s1  <<<dim3(64,32), 64, 0, stream>>>(g_rna, c1w, S1);
  k_s2  <<<dim3(64,32), 64, 0, stream>>>(l_rna, c2w, S2);
  k_y1  <<<dim3(64,32), 128, 0, stream>>>(S1, emb1, c1b, ysum);
  k_y2  <<<dim3(64,32), 128, 0, stream>>>(S2, emb2, c2b, ysum);
  k_fcxr<<<64, 256, 0, stream>>>(ysum, fcxw, fcxb, out);
}

// Round 5
// 887.891 us; speedup vs baseline: 2.0880x; 1.3611x over previous
//
#include <hip/hip_runtime.h>

#define N_NODES 50000
#define N_EDGES 800000
#define LRELU_SLOPE 0.2f
#define BN_EPS 1e-5f

__device__ __forceinline__ float lrelu(float x){ return fmaxf(x,0.f) + LRELU_SLOPE*fminf(x,0.f); }
__device__ __forceinline__ float wsum(float v){
  #pragma unroll
  for(int m=32;m>=1;m>>=1) v += __shfl_xor(v, m, 64);
  return v;
}

// ---------------- CSR build ----------------
__global__ __launch_bounds__(256) void k_init(int* __restrict__ cnt, int* __restrict__ fill,
                                              int* __restrict__ gstart, int* __restrict__ gend){
  int i = blockIdx.x*256 + threadIdx.x;
  if(i < N_NODES){ cnt[i] = 0; fill[i] = 0; }
  if(i < 64){ gstart[i] = N_NODES; gend[i] = 0; }
}

__global__ __launch_bounds__(256) void k_hist(const int* __restrict__ eidx, int* __restrict__ cnt){
  int e = blockIdx.x*256 + threadIdx.x;
  if(e < N_EDGES) atomicAdd(&cnt[eidx[N_EDGES + e]], 1);
}

__global__ __launch_bounds__(1024) void k_scan(const int* __restrict__ cnt, int* __restrict__ rowptr){
  __shared__ int part[1024];
  int t = threadIdx.x;
  const int per = (N_NODES + 1023)/1024; // 49
  int beg = t*per, end = beg+per; if(end > N_NODES) end = N_NODES;
  int s = 0;
  for(int i=beg;i<end;i++) s += cnt[i];
  part[t] = s;
  __syncthreads();
  for(int off=1; off<1024; off<<=1){
    int v = (t>=off) ? part[t-off] : 0;
    __syncthreads();
    part[t] += v;
    __syncthreads();
  }
  int run = (t==0) ? 0 : part[t-1];
  for(int i=beg;i<end;i++){ rowptr[i] = run; run += cnt[i]; }
  if(t==1023) rowptr[N_NODES] = run;
}

__global__ __launch_bounds__(256) void k_scatter(const int* __restrict__ eidx, const float* __restrict__ pw,
                                                 const int* __restrict__ rowptr, int* __restrict__ fill,
                                                 int* __restrict__ s_src, float* __restrict__ s_w){
  int e = blockIdx.x*256 + threadIdx.x;
  if(e < N_EDGES){
    int d = eidx[N_EDGES + e];
    int pos = rowptr[d] + atomicAdd(&fill[d], 1);
    s_src[pos] = eidx[e];
    s_w[pos]   = pw[e];
  }
}

// ---------------- GCN ----------------
__global__ __launch_bounds__(256) void k_deg(const int* __restrict__ rowptr, const float* __restrict__ s_w,
                                             float* __restrict__ dinv){
  int n = blockIdx.x*256 + threadIdx.x;
  if(n >= N_NODES) return;
  int rb = rowptr[n], re = rowptr[n+1];
  float d = 1.f; // self-loop weight
  for(int j=rb;j<re;j++) d += s_w[j];
  dinv[n] = 1.f / sqrtf(d);
}

__global__ __launch_bounds__(256) void k_enorm(const int* __restrict__ s_src, const float* __restrict__ s_w,
                                               const float* __restrict__ dinv, float* __restrict__ g_e){
  int j = blockIdx.x*256 + threadIdx.x;
  if(j < N_EDGES) g_e[j] = dinv[s_src[j]] * s_w[j];
}

__global__ __launch_bounds__(256) void k_h(const float* __restrict__ px, const float* __restrict__ gw,
                                           float* __restrict__ h){
  int n = blockIdx.x*256 + threadIdx.x;
  if(n >= N_NODES) return;
  float x[33];
  #pragma unroll
  for(int k=0;k<33;k++) x[k] = px[n*33+k];
  for(int c=0;c<33;c++){
    float a = 0.f;
    #pragma unroll
    for(int k=0;k<33;k++) a = fmaf(x[k], gw[c*33+k], a);
    h[n*33+c] = a;
  }
}

// xp1 padded to stride 36, fused: agg + gcn_b + relu + BN(eval)
__global__ __launch_bounds__(256) void k_gcn(const float* __restrict__ h, const int* __restrict__ rowptr,
                                             const int* __restrict__ s_src, const float* __restrict__ g_e,
                                             const float* __restrict__ dinv,
                                             const float* __restrict__ gcnb, const float* __restrict__ bnm,
                                             const float* __restrict__ bnv, const float* __restrict__ bnw,
                                             const float* __restrict__ bnb, float* __restrict__ xp1){
  int t = threadIdx.x;
  int nl = t/33, c = t - nl*33;
  int n = blockIdx.x*7 + nl;
  if(nl < 7 && n < N_NODES){
    float acc = 0.f;
    int rb = rowptr[n], re = rowptr[n+1];
    for(int j=rb;j<re;j++) acc = fmaf(g_e[j], h[s_src[j]*33 + c], acc);
    float dn = dinv[n];
    acc += dn * h[n*33 + c];
    float val = fmaxf(dn*acc + gcnb[c], 0.f);
    float inv = bnw[c] / sqrtf(bnv[c] + BN_EPS);
    val = val*inv + (bnb[c] - bnm[c]*inv);
    xp1[n*36 + c] = val;
  }
  int p = t - 231;
  if(p >= 0 && p < 21){
    int np = blockIdx.x*7 + p/3;
    if(np < N_NODES) xp1[np*36 + 33 + (p%3)] = 0.f;
  }
}

// ---------------- GATv2 ----------------
// Tiled: 64 nodes/block, x-tile + both weight matrices in LDS, coalesced flat writes.
__global__ __launch_bounds__(256) void k_gatlin(const float* __restrict__ xp1, const float* __restrict__ wl,
                                                const float* __restrict__ wr, float* __restrict__ xl,
                                                float* __restrict__ xr){
  __shared__ float sx[64*36];    // 9 KB
  __shared__ float swl[132*33];  // 17.4 KB
  __shared__ float swr[132*33];  // 17.4 KB
  int t = threadIdx.x;
  int n0 = blockIdx.x*64;
  int nn = N_NODES - n0; if(nn > 64) nn = 64;
  for(int i=t;i<4356;i+=256){ swl[i] = wl[i]; swr[i] = wr[i]; }
  int xcnt = nn*36;
  for(int i=t;i<xcnt;i+=256) sx[i] = xp1[(size_t)n0*36 + i];
  __syncthreads();
  int total = nn*132;
  for(int flat=t; flat<total; flat+=256){
    int n = flat/132, j = flat - n*132;
    const float* xv = sx + n*36;
    const float* wlv = swl + j*33;
    const float* wrv = swr + j*33;
    float al = 0.f, ar = 0.f;
    #pragma unroll
    for(int k=0;k<33;k++){
      float x = xv[k];
      al = fmaf(x, wlv[k], al);
      ar = fmaf(x, wrv[k], ar);
    }
    size_t gidx = (size_t)n0*132 + flat;
    xl[gidx] = al;
    xr[gidx] = ar;
  }
}

// one block per node; wave 0 = head 0, wave 1 = head 1; lane = channel (c<64, lanes 0/1 also do c=64,65)
__global__ __launch_bounds__(128) void k_gat(const int* __restrict__ rowptr, const int* __restrict__ s_src,
                                             const float* __restrict__ xl, const float* __restrict__ xr,
                                             const float* __restrict__ att, const float* __restrict__ gatb,
                                             float* __restrict__ xp2){
  int n = blockIdx.x;
  int h = threadIdx.x >> 6;
  int lane = threadIdx.x & 63;
  int base = h*66;
  bool ex = (lane < 2);
  float att0 = att[base + lane];
  float att1 = ex ? att[base + 64 + lane] : 0.f;
  size_t nrow = (size_t)n*132;
  float xr0 = xr[nrow + base + lane];
  float xr1 = ex ? xr[nrow + base + 64 + lane] : 0.f;
  // self-loop edge
  float xs0 = xl[nrow + base + lane];
  float xs1 = ex ? xl[nrow + base + 64 + lane] : 0.f;
  float tsum = lrelu(xs0+xr0)*att0 + lrelu(xs1+xr1)*att1;
  float e_self = wsum(tsum);
  float acc0 = xs0, acc1 = xs1, asum = 1.f; // a_self = exp(0) = 1
  int rb = rowptr[n], re = rowptr[n+1];
  for(int j=rb;j<re;j++){
    int s = s_src[j];
    size_t srow = (size_t)s*132;
    float v0 = xl[srow + base + lane];
    float v1 = ex ? xl[srow + base + 64 + lane] : 0.f;
    float tt = lrelu(v0+xr0)*att0 + lrelu(v1+xr1)*att1;
    float e = wsum(tt);
    float a = __expf(e - e_self);
    acc0 = fmaf(a, v0, acc0);
    acc1 = fmaf(a, v1, acc1);
    asum += a;
  }
  float inv = 1.f/asum;
  float o0 = fmaxf(acc0*inv + gatb[base + lane], 0.f);
  xp2[nrow + base + lane] = o0;
  if(ex){
    float o1 = fmaxf(acc1*inv + gatb[base + 64 + lane], 0.f);
    xp2[nrow + base + 64 + lane] = o1;
  }
}

// ---------------- pooling + MLP head ----------------
// pro_batch is SORTED -> boundary detection, zero atomics
__global__ __launch_bounds__(256) void k_bounds(const int* __restrict__ batch, int* __restrict__ gstart,
                                                int* __restrict__ gend){
  int n = blockIdx.x*256 + threadIdx.x;
  if(n >= N_NODES) return;
  int b = batch[n];
  if(n == 0) gstart[b] = 0;
  else {
    int p = batch[n-1];
    if(p != b){ gstart[b] = n; gend[p] = n; }
  }
  if(n == N_NODES-1) gend[b] = N_NODES;
}

// stage 1: 16 segments per graph -> partial sums (1024 blocks)
__global__ __launch_bounds__(128) void k_poolp(const float* __restrict__ xp2, const int* __restrict__ gstart,
                                               const int* __restrict__ gend, float* __restrict__ pp){
  int g = blockIdx.x, seg = blockIdx.y, t = threadIdx.x;
  int s = gstart[g], e = gend[g];
  int len = e - s; if(len < 0) len = 0;
  int ns = s + (int)(((long long)len*seg)>>4);
  int ne = s + (int)(((long long)len*(seg+1))>>4);
  float a0 = 0.f, a1 = 0.f;
  for(int n=ns;n<ne;n++){
    a0 += xp2[(size_t)n*132 + t];
    if(t < 4) a1 += xp2[(size_t)n*132 + 128 + t];
  }
  float* o = pp + (size_t)(g*16 + seg)*132;
  o[t] = a0;
  if(t < 4) o[128 + t] = a1;
}

// stage 2: reduce 16 partials, divide by count
__global__ __launch_bounds__(256) void k_poolr(const float* __restrict__ pp, const int* __restrict__ gstart,
                                               const int* __restrict__ gend, float* __restrict__ pooledT){
  int g = blockIdx.x, t = threadIdx.x;
  if(t >= 132) return;
  float s = 0.f;
  #pragma unroll
  for(int k=0;k<16;k++) s += pp[(size_t)(g*16 + k)*132 + t];
  int c = gend[g] - gstart[g]; if(c < 1) c = 1;
  pooledT[t*64 + g] = s/(float)c;
}

__global__ __launch_bounds__(256) void k_fc1(const float* __restrict__ pooledT, const float* __restrict__ w,
                                             const float* __restrict__ b, float* __restrict__ h1T){
  int gid = blockIdx.x*256 + threadIdx.x;
  int o = gid >> 6, g = gid & 63;
  float acc = b[o];
  const float* wr = w + o*132;
  for(int k=0;k<132;k++) acc = fmaf(pooledT[k*64+g], wr[k], acc);
  h1T[o*64+g] = fmaxf(acc, 0.f);
}

__global__ __launch_bounds__(256) void k_fc2(const float* __restrict__ h1T, const float* __restrict__ w,
                                             const float* __restrict__ b, float* __restrict__ out){
  int gid = blockIdx.x*256 + threadIdx.x;
  int o = gid >> 6, g = gid & 63;
  float acc = b[o];
  const float* wr = w + o*1024;
  for(int k=0;k<1024;k++) acc = fmaf(h1T[k*64+g], wr[k], acc);
  out[8192 + g*128 + o] = acc;
}

// ---------------- RNA branches ----------------
// Coalesced, atomic-free bucketed segment-sum (octet-privatized LDS).
__global__ __launch_bounds__(64) void k_s1(const int* __restrict__ g, const float* __restrict__ w,
                                           float* __restrict__ S1){
  __shared__ float Sp[320]; // [o=8][v=5][k=8]
  int b = blockIdx.x, co = blockIdx.y, lane = threadIdx.x;
  for(int i=lane;i<320;i+=64) Sp[i]=0.f;
  __syncthreads();
  const float* wrow = w + co*24000;
  const int*   grow = g + b*3000;
  int ob = (lane>>3)*40, kk = lane&7;
  for(int iter=0; iter<375; ++iter){
    int idx = iter*64 + lane;
    float wv = wrow[idx];
    int v = grow[idx>>3];
    Sp[ob + v*8 + kk] += wv;
  }
  __syncthreads();
  if(lane < 40){
    float s = 0.f;
    #pragma unroll
    for(int o=0;o<8;o++) s += Sp[o*40 + lane];
    S1[b*1280 + co*40 + lane] = s;
  }
}

__global__ __launch_bounds__(64) void k_s2(const int* __restrict__ g, const float* __restrict__ w,
                                           float* __restrict__ S2){
  __shared__ float Sp[4160]; // [o=8][v=65][k=8]
  int b = blockIdx.x, co = blockIdx.y, lane = threadIdx.x;
  for(int i=lane;i<4160;i+=64) Sp[i]=0.f;
  __syncthreads();
  const float* wrow = w + co*23984;
  const int*   grow = g + b*2998;
  int ob = (lane>>3)*520, kk = lane&7;
  for(int iter=0; iter<375; ++iter){
    int idx = iter*64 + lane;
    if(idx < 23984){
      float wv = wrow[idx];
      int v = grow[idx>>3];
      Sp[ob + v*8 + kk] += wv;
    }
  }
  __syncthreads();
  for(int r=0;r<9;r++){
    int j = r*64 + lane;
    if(j < 520){
      float s = 0.f;
      #pragma unroll
      for(int o=0;o<8;o++) s += Sp[o*520 + j];
      S2[(size_t)b*16640 + co*520 + j] = s;
    }
  }
}

// ysum[b][co*121+l] = 0.5*(conv1+bias1)   (k_y1 writes, k_y2 adds)
__global__ __launch_bounds__(128) void k_y1(const float* __restrict__ S1, const float* __restrict__ emb1,
                                            const float* __restrict__ c1b, float* __restrict__ ysum){
  int b = blockIdx.x, co = blockIdx.y, t = threadIdx.x;
  __shared__ float em[640];
  for(int i=t;i<640;i+=128) em[i] = emb1[i];
  __syncthreads();
  if(t < 121){
    const float* S = S1 + b*1280 + co*40;
    float acc = c1b[co];
    #pragma unroll
    for(int v=0;v<5;v++)
      #pragma unroll
      for(int k=0;k<8;k++) acc = fmaf(S[v*8+k], em[v*128 + t + k], acc);
    ysum[b*3872 + co*121 + t] = 0.5f*acc;
  }
}

__global__ __launch_bounds__(128) void k_y2(const float* __restrict__ S2, const float* __restrict__ emb2,
                                            const float* __restrict__ c2b, float* __restrict__ ysum){
  int b = blockIdx.x, co = blockIdx.y, t = threadIdx.x;
  __shared__ float em[8320];
  for(int i=t;i<8320;i+=128) em[i] = emb2[i];
  __syncthreads();
  if(t < 121){
    const float* S = S2 + (size_t)b*16640 + co*520;
    float acc = c2b[co];
    for(int v=0;v<65;v++){
      #pragma unroll
      for(int k=0;k<8;k++) acc = fmaf(S[v*8+k], em[v*128 + t + k], acc);
    }
    ysum[b*3872 + co*121 + t] += 0.5f*acc;
  }
}

// out[b][o] = sum_j ysum[b][j]*fcw[o][j] + fcb[o]  (float4 streams)
__global__ __launch_bounds__(256) void k_fcxr(const float* __restrict__ ysum, const float* __restrict__ fcw,
                                              const float* __restrict__ fcb, float* __restrict__ out){
  __shared__ float part[256];
  int b = blockIdx.x, t = threadIdx.x;
  int o = t & 127, half = t >> 7;
  const float4* ys = (const float4*)(ysum + b*3872 + half*1936);
  const float4* wr = (const float4*)(fcw + o*3872 + half*1936);
  float acc = 0.f;
  for(int k=0;k<484;k++){
    float4 y = ys[k], q = wr[k];
    acc += y.x*q.x + y.y*q.y + y.z*q.z + y.w*q.w;
  }
  part[t] = acc;
  __syncthreads();
  if(t < 128) out[b*128 + t] = part[t] + part[128+t] + fcb[t];
}

extern "C" void kernel_launch(void* const* d_in, const int* in_sizes, int n_in,
                              void* d_out, int out_size, void* d_ws, size_t ws_size,
                              hipStream_t stream){
  const int*   g_rna = (const int*)  d_in[0];
  const int*   l_rna = (const int*)  d_in[1];
  const float* pro_x = (const float*)d_in[2];
  const int*   eidx  = (const int*)  d_in[3];
  const float* pro_w = (const float*)d_in[4];
  const int*   batch = (const int*)  d_in[5];
  const float* emb1  = (const float*)d_in[6];
  const float* emb2  = (const float*)d_in[7];
  const float* c1w   = (const float*)d_in[8];
  const float* c1b   = (const float*)d_in[9];
  const float* c2w   = (const float*)d_in[10];
  const float* c2b   = (const float*)d_in[11];
  const float* fcxw  = (const float*)d_in[12];
  const float* fcxb  = (const float*)d_in[13];
  const float* gcnw  = (const float*)d_in[14];
  const float* gcnb  = (const float*)d_in[15];
  const float* bnm   = (const float*)d_in[16];
  const float* bnv   = (const float*)d_in[17];
  const float* bnw   = (const float*)d_in[18];
  const float* bnb   = (const float*)d_in[19];
  const float* gwl   = (const float*)d_in[20];
  const float* gwr   = (const float*)d_in[21];
  const float* gatt  = (const float*)d_in[22];
  const float* gatb  = (const float*)d_in[23];
  const float* f1w   = (const float*)d_in[24];
  const float* f1b   = (const float*)d_in[25];
  const float* f2w   = (const float*)d_in[26];
  const float* f2b_  = (const float*)d_in[27];
  float* out = (float*)d_out;

  char* ws = (char*)d_ws;
  size_t off = 0;
  auto A = [&](size_t n)->char*{ char* p = ws + off; off = (off + n + 255) & ~(size_t)255; return p; };
  int*   cnt    = (int*)  A((size_t)N_NODES*4);
  int*   rowptr = (int*)  A((size_t)(N_NODES+1)*4);
  int*   fill   = (int*)  A((size_t)N_NODES*4);
  int*   s_src  = (int*)  A((size_t)N_EDGES*4);
  float* s_w    = (float*)A((size_t)N_EDGES*4);
  float* g_e    = (float*)A((size_t)N_EDGES*4);
  float* dinv   = (float*)A((size_t)N_NODES*4);
  float* hbuf   = (float*)A((size_t)N_NODES*33*4);
  float* xp1    = (float*)A((size_t)N_NODES*36*4);
  float* xl     = (float*)A((size_t)N_NODES*132*4);
  float* xr     = (float*)A((size_t)N_NODES*132*4);
  float* xp2    = (float*)A((size_t)N_NODES*132*4);
  int*   gstart = (int*)  A(64*4);
  int*   gend   = (int*)  A(64*4);
  float* pooledT= (float*)A(132*64*4);
  float* pp     = (float*)A((size_t)64*16*132*4);
  float* h1T    = (float*)A(1024*64*4);
  float* S1     = (float*)A((size_t)64*1280*4);
  float* S2     = (float*)A((size_t)64*16640*4);
  float* ysum   = (float*)A((size_t)64*3872*4);
  (void)ws_size; (void)in_sizes; (void)n_in; (void)out_size;

  // protein GNN pipeline
  k_init   <<<196, 256, 0, stream>>>(cnt, fill, gstart, gend);
  k_hist   <<<3125, 256, 0, stream>>>(eidx, cnt);
  k_scan   <<<1, 1024, 0, stream>>>(cnt, rowptr);
  k_scatter<<<3125, 256, 0, stream>>>(eidx, pro_w, rowptr, fill, s_src, s_w);
  k_deg    <<<196, 256, 0, stream>>>(rowptr, s_w, dinv);
  k_enorm  <<<3125, 256, 0, stream>>>(s_src, s_w, dinv, g_e);
  k_h      <<<196, 256, 0, stream>>>(pro_x, gcnw, hbuf);
  k_gcn    <<<7143, 256, 0, stream>>>(hbuf, rowptr, s_src, g_e, dinv, gcnb, bnm, bnv, bnw, bnb, xp1);
  k_gatlin <<<782, 256, 0, stream>>>(xp1, gwl, gwr, xl, xr);
  k_gat    <<<N_NODES, 128, 0, stream>>>(rowptr, s_src, xl, xr, gatt, gatb, xp2);
  k_bounds <<<196, 256, 0, stream>>>(batch, gstart, gend);
  k_poolp  <<<dim3(64,16), 128, 0, stream>>>(xp2, gstart, gend, pp);
  k_poolr  <<<64, 256, 0, stream>>>(pp, gstart, gend, pooledT);
  k_fc1    <<<256, 256, 0, stream>>>(pooledT, f1w, f1b, h1T);
  k_fc2    <<<32, 256, 0, stream>>>(h1T, f2w, f2b_, out);

  // RNA branches
  k_s1  <<<dim3(64,32), 64, 0, stream>>>(g_rna, c1w, S1);
  k_s2  <<<dim3(64,32), 64, 0, stream>>>(l_rna, c2w, S2);
  k_y1  <<<dim3(64,32), 128, 0, stream>>>(S1, emb1, c1b, ysum);
  k_y2  <<<dim3(64,32), 128, 0, stream>>>(S2, emb2, c2b, ysum);
  k_fcxr<<<64, 256, 0, stream>>>(ysum, fcxw, fcxb, out);
}

// Round 6
// 840.283 us; speedup vs baseline: 2.2063x; 1.0567x over previous
//
#include <hip/hip_runtime.h>

#define N_NODES 50000
#define N_EDGES 800000
#define LRELU_SLOPE 0.2f
#define BN_EPS 1e-5f

__device__ __forceinline__ float lrelu(float x){ return fmaxf(x,0.f) + LRELU_SLOPE*fminf(x,0.f); }
__device__ __forceinline__ float wsum(float v){
  #pragma unroll
  for(int m=32;m>=1;m>>=1) v += __shfl_xor(v, m, 64);
  return v;
}

// ---------------- CSR build ----------------
__global__ __launch_bounds__(256) void k_init(int* __restrict__ cnt, int* __restrict__ fill,
                                              int* __restrict__ gstart, int* __restrict__ gend){
  int i = blockIdx.x*256 + threadIdx.x;
  if(i < N_NODES){ cnt[i] = 0; fill[i] = 0; }
  if(i < 64){ gstart[i] = N_NODES; gend[i] = 0; }
}

__global__ __launch_bounds__(256) void k_hist(const int* __restrict__ eidx, int* __restrict__ cnt){
  int e = blockIdx.x*256 + threadIdx.x;
  if(e < N_EDGES) atomicAdd(&cnt[eidx[N_EDGES + e]], 1);
}

__global__ __launch_bounds__(1024) void k_scan(const int* __restrict__ cnt, int* __restrict__ rowptr){
  __shared__ int part[1024];
  int t = threadIdx.x;
  const int per = (N_NODES + 1023)/1024; // 49
  int beg = t*per, end = beg+per; if(end > N_NODES) end = N_NODES;
  int s = 0;
  for(int i=beg;i<end;i++) s += cnt[i];
  part[t] = s;
  __syncthreads();
  for(int off=1; off<1024; off<<=1){
    int v = (t>=off) ? part[t-off] : 0;
    __syncthreads();
    part[t] += v;
    __syncthreads();
  }
  int run = (t==0) ? 0 : part[t-1];
  for(int i=beg;i<end;i++){ rowptr[i] = run; run += cnt[i]; }
  if(t==1023) rowptr[N_NODES] = run;
}

__global__ __launch_bounds__(256) void k_scatter(const int* __restrict__ eidx, const float* __restrict__ pw,
                                                 const int* __restrict__ rowptr, int* __restrict__ fill,
                                                 int* __restrict__ s_src, float* __restrict__ s_w){
  int e = blockIdx.x*256 + threadIdx.x;
  if(e < N_EDGES){
    int d = eidx[N_EDGES + e];
    int pos = rowptr[d] + atomicAdd(&fill[d], 1);
    s_src[pos] = eidx[e];
    s_w[pos]   = pw[e];
  }
}

// ---------------- GCN ----------------
__global__ __launch_bounds__(256) void k_deg(const int* __restrict__ rowptr, const float* __restrict__ s_w,
                                             float* __restrict__ dinv){
  int n = blockIdx.x*256 + threadIdx.x;
  if(n >= N_NODES) return;
  int rb = rowptr[n], re = rowptr[n+1];
  float d = 1.f; // self-loop weight
  for(int j=rb;j<re;j++) d += s_w[j];
  dinv[n] = 1.f / sqrtf(d);
}

__global__ __launch_bounds__(256) void k_enorm(const int* __restrict__ s_src, const float* __restrict__ s_w,
                                               const float* __restrict__ dinv, float* __restrict__ g_e){
  int j = blockIdx.x*256 + threadIdx.x;
  if(j < N_EDGES) g_e[j] = dinv[s_src[j]] * s_w[j];
}

__global__ __launch_bounds__(256) void k_h(const float* __restrict__ px, const float* __restrict__ gw,
                                           float* __restrict__ h){
  int n = blockIdx.x*256 + threadIdx.x;
  if(n >= N_NODES) return;
  float x[33];
  #pragma unroll
  for(int k=0;k<33;k++) x[k] = px[n*33+k];
  for(int c=0;c<33;c++){
    float a = 0.f;
    #pragma unroll
    for(int k=0;k<33;k++) a = fmaf(x[k], gw[c*33+k], a);
    h[n*33+c] = a;
  }
}

// xp1 padded to stride 36, fused: agg + gcn_b + relu + BN(eval)
__global__ __launch_bounds__(256) void k_gcn(const float* __restrict__ h, const int* __restrict__ rowptr,
                                             const int* __restrict__ s_src, const float* __restrict__ g_e,
                                             const float* __restrict__ dinv,
                                             const float* __restrict__ gcnb, const float* __restrict__ bnm,
                                             const float* __restrict__ bnv, const float* __restrict__ bnw,
                                             const float* __restrict__ bnb, float* __restrict__ xp1){
  int t = threadIdx.x;
  int nl = t/33, c = t - nl*33;
  int n = blockIdx.x*7 + nl;
  if(nl < 7 && n < N_NODES){
    float acc = 0.f;
    int rb = rowptr[n], re = rowptr[n+1];
    for(int j=rb;j<re;j++) acc = fmaf(g_e[j], h[s_src[j]*33 + c], acc);
    float dn = dinv[n];
    acc += dn * h[n*33 + c];
    float val = fmaxf(dn*acc + gcnb[c], 0.f);
    float inv = bnw[c] / sqrtf(bnv[c] + BN_EPS);
    val = val*inv + (bnb[c] - bnm[c]*inv);
    xp1[n*36 + c] = val;
  }
  int p = t - 231;
  if(p >= 0 && p < 21){
    int np = blockIdx.x*7 + p/3;
    if(np < N_NODES) xp1[np*36 + 33 + (p%3)] = 0.f;
  }
}

// ---------------- GATv2 ----------------
// Tiled: 64 nodes/block, x-tile + both weight matrices in LDS, coalesced flat writes.
__global__ __launch_bounds__(256) void k_gatlin(const float* __restrict__ xp1, const float* __restrict__ wl,
                                                const float* __restrict__ wr, float* __restrict__ xl,
                                                float* __restrict__ xr){
  __shared__ float sx[64*36];    // 9 KB
  __shared__ float swl[132*33];  // 17.4 KB
  __shared__ float swr[132*33];  // 17.4 KB
  int t = threadIdx.x;
  int n0 = blockIdx.x*64;
  int nn = N_NODES - n0; if(nn > 64) nn = 64;
  for(int i=t;i<4356;i+=256){ swl[i] = wl[i]; swr[i] = wr[i]; }
  int xcnt = nn*36;
  for(int i=t;i<xcnt;i+=256) sx[i] = xp1[(size_t)n0*36 + i];
  __syncthreads();
  int total = nn*132;
  for(int flat=t; flat<total; flat+=256){
    int n = flat/132, j = flat - n*132;
    const float* xv = sx + n*36;
    const float* wlv = swl + j*33;
    const float* wrv = swr + j*33;
    float al = 0.f, ar = 0.f;
    #pragma unroll
    for(int k=0;k<33;k++){
      float x = xv[k];
      al = fmaf(x, wlv[k], al);
      ar = fmaf(x, wrv[k], ar);
    }
    size_t gidx = (size_t)n0*132 + flat;
    xl[gidx] = al;
    xr[gidx] = ar;
  }
}

// one block per node; wave 0 = head 0, wave 1 = head 1; lane = channel.
// 4-way edge unroll: 4 independent gathers + 4 interleaved butterfly reduces per iter.
__global__ __launch_bounds__(128) void k_gat(const int* __restrict__ rowptr, const int* __restrict__ s_src,
                                             const float* __restrict__ xl, const float* __restrict__ xr,
                                             const float* __restrict__ att, const float* __restrict__ gatb,
                                             float* __restrict__ xp2){
  int n = blockIdx.x;
  int h = threadIdx.x >> 6;
  int lane = threadIdx.x & 63;
  int base = h*66;
  bool ex = (lane < 2);
  float att0 = att[base + lane];
  float att1 = ex ? att[base + 64 + lane] : 0.f;
  size_t nrow = (size_t)n*132;
  float xr0 = xr[nrow + base + lane];
  float xr1 = ex ? xr[nrow + base + 64 + lane] : 0.f;
  float xs0 = xl[nrow + base + lane];
  float xs1 = ex ? xl[nrow + base + 64 + lane] : 0.f;
  float e_self = wsum(lrelu(xs0+xr0)*att0 + lrelu(xs1+xr1)*att1);
  float acc0 = xs0, acc1 = xs1, asum = 1.f; // a_self = exp(0) = 1
  int rb = rowptr[n], re = rowptr[n+1];
  int j = rb;
  for(; j+4 <= re; j += 4){
    int sA = s_src[j], sB = s_src[j+1], sC = s_src[j+2], sD = s_src[j+3];
    const float* rA = xl + (size_t)sA*132 + base;
    const float* rB = xl + (size_t)sB*132 + base;
    const float* rC = xl + (size_t)sC*132 + base;
    const float* rD = xl + (size_t)sD*132 + base;
    float vA0 = rA[lane], vB0 = rB[lane], vC0 = rC[lane], vD0 = rD[lane];
    float vA1 = ex ? rA[64+lane] : 0.f;
    float vB1 = ex ? rB[64+lane] : 0.f;
    float vC1 = ex ? rC[64+lane] : 0.f;
    float vD1 = ex ? rD[64+lane] : 0.f;
    float t0 = lrelu(vA0+xr0)*att0 + lrelu(vA1+xr1)*att1;
    float t1 = lrelu(vB0+xr0)*att0 + lrelu(vB1+xr1)*att1;
    float t2 = lrelu(vC0+xr0)*att0 + lrelu(vC1+xr1)*att1;
    float t3 = lrelu(vD0+xr0)*att0 + lrelu(vD1+xr1)*att1;
    #pragma unroll
    for(int m=32;m>=1;m>>=1){
      t0 += __shfl_xor(t0, m, 64);
      t1 += __shfl_xor(t1, m, 64);
      t2 += __shfl_xor(t2, m, 64);
      t3 += __shfl_xor(t3, m, 64);
    }
    float a0 = __expf(t0 - e_self);
    float a1 = __expf(t1 - e_self);
    float a2 = __expf(t2 - e_self);
    float a3 = __expf(t3 - e_self);
    acc0 = fmaf(a0, vA0, fmaf(a1, vB0, fmaf(a2, vC0, fmaf(a3, vD0, acc0))));
    acc1 = fmaf(a0, vA1, fmaf(a1, vB1, fmaf(a2, vC1, fmaf(a3, vD1, acc1))));
    asum += (a0 + a1) + (a2 + a3);
  }
  for(; j<re; j++){
    int s = s_src[j];
    size_t srow = (size_t)s*132;
    float v0 = xl[srow + base + lane];
    float v1 = ex ? xl[srow + base + 64 + lane] : 0.f;
    float e = wsum(lrelu(v0+xr0)*att0 + lrelu(v1+xr1)*att1);
    float a = __expf(e - e_self);
    acc0 = fmaf(a, v0, acc0);
    acc1 = fmaf(a, v1, acc1);
    asum += a;
  }
  float inv = 1.f/asum;
  float o0 = fmaxf(acc0*inv + gatb[base + lane], 0.f);
  xp2[nrow + base + lane] = o0;
  if(ex){
    float o1 = fmaxf(acc1*inv + gatb[base + 64 + lane], 0.f);
    xp2[nrow + base + 64 + lane] = o1;
  }
}

// ---------------- pooling + MLP head ----------------
// pro_batch is SORTED -> boundary detection, zero atomics
__global__ __launch_bounds__(256) void k_bounds(const int* __restrict__ batch, int* __restrict__ gstart,
                                                int* __restrict__ gend){
  int n = blockIdx.x*256 + threadIdx.x;
  if(n >= N_NODES) return;
  int b = batch[n];
  if(n == 0) gstart[b] = 0;
  else {
    int p = batch[n-1];
    if(p != b){ gstart[b] = n; gend[p] = n; }
  }
  if(n == N_NODES-1) gend[b] = N_NODES;
}

// stage 1: 16 segments per graph -> partial sums (1024 blocks)
__global__ __launch_bounds__(128) void k_poolp(const float* __restrict__ xp2, const int* __restrict__ gstart,
                                               const int* __restrict__ gend, float* __restrict__ pp){
  int g = blockIdx.x, seg = blockIdx.y, t = threadIdx.x;
  int s = gstart[g], e = gend[g];
  int len = e - s; if(len < 0) len = 0;
  int ns = s + (int)(((long long)len*seg)>>4);
  int ne = s + (int)(((long long)len*(seg+1))>>4);
  float a0 = 0.f, a1 = 0.f;
  for(int n=ns;n<ne;n++){
    a0 += xp2[(size_t)n*132 + t];
    if(t < 4) a1 += xp2[(size_t)n*132 + 128 + t];
  }
  float* o = pp + (size_t)(g*16 + seg)*132;
  o[t] = a0;
  if(t < 4) o[128 + t] = a1;
}

// stage 2: reduce 16 partials, divide by count
__global__ __launch_bounds__(256) void k_poolr(const float* __restrict__ pp, const int* __restrict__ gstart,
                                               const int* __restrict__ gend, float* __restrict__ pooledT){
  int g = blockIdx.x, t = threadIdx.x;
  if(t >= 132) return;
  float s = 0.f;
  #pragma unroll
  for(int k=0;k<16;k++) s += pp[(size_t)(g*16 + k)*132 + t];
  int c = gend[g] - gstart[g]; if(c < 1) c = 1;
  pooledT[t*64 + g] = s/(float)c;
}

__global__ __launch_bounds__(256) void k_fc1(const float* __restrict__ pooledT, const float* __restrict__ w,
                                             const float* __restrict__ b, float* __restrict__ h1T){
  int gid = blockIdx.x*256 + threadIdx.x;
  int o = gid >> 6, g = gid & 63;
  float acc = b[o];
  const float* wr = w + o*132;
  for(int k=0;k<132;k++) acc = fmaf(pooledT[k*64+g], wr[k], acc);
  h1T[o*64+g] = fmaxf(acc, 0.f);
}

__global__ __launch_bounds__(256) void k_fc2(const float* __restrict__ h1T, const float* __restrict__ w,
                                             const float* __restrict__ b, float* __restrict__ out){
  int gid = blockIdx.x*256 + threadIdx.x;
  int o = gid >> 6, g = gid & 63;
  float acc = b[o];
  const float* wr = w + o*1024;
  for(int k=0;k<1024;k++) acc = fmaf(h1T[k*64+g], wr[k], acc);
  out[8192 + g*128 + o] = acc;
}

// ---------------- RNA branches ----------------
// Coalesced, atomic-free bucketed segment-sum (octet-privatized LDS).
__global__ __launch_bounds__(64) void k_s1(const int* __restrict__ g, const float* __restrict__ w,
                                           float* __restrict__ S1){
  __shared__ float Sp[320]; // [o=8][v=5][k=8]
  int b = blockIdx.x, co = blockIdx.y, lane = threadIdx.x;
  for(int i=lane;i<320;i+=64) Sp[i]=0.f;
  __syncthreads();
  const float* wrow = w + co*24000;
  const int*   grow = g + b*3000;
  int ob = (lane>>3)*40, kk = lane&7;
  for(int iter=0; iter<375; ++iter){
    int idx = iter*64 + lane;
    float wv = wrow[idx];
    int v = grow[idx>>3];
    Sp[ob + v*8 + kk] += wv;
  }
  __syncthreads();
  if(lane < 40){
    float s = 0.f;
    #pragma unroll
    for(int o=0;o<8;o++) s += Sp[o*40 + lane];
    S1[b*1280 + co*40 + lane] = s;
  }
}

__global__ __launch_bounds__(64) void k_s2(const int* __restrict__ g, const float* __restrict__ w,
                                           float* __restrict__ S2){
  __shared__ float Sp[4160]; // [o=8][v=65][k=8]
  int b = blockIdx.x, co = blockIdx.y, lane = threadIdx.x;
  for(int i=lane;i<4160;i+=64) Sp[i]=0.f;
  __syncthreads();
  const float* wrow = w + co*23984;
  const int*   grow = g + b*2998;
  int ob = (lane>>3)*520, kk = lane&7;
  for(int iter=0; iter<375; ++iter){
    int idx = iter*64 + lane;
    if(idx < 23984){
      float wv = wrow[idx];
      int v = grow[idx>>3];
      Sp[ob + v*8 + kk] += wv;
    }
  }
  __syncthreads();
  for(int r=0;r<9;r++){
    int j = r*64 + lane;
    if(j < 520){
      float s = 0.f;
      #pragma unroll
      for(int o=0;o<8;o++) s += Sp[o*520 + j];
      S2[(size_t)b*16640 + co*520 + j] = s;
    }
  }
}

// ysum[b][co*121+l] = 0.5*(conv1+bias1)   (k_y1 writes, k_y2 adds)
__global__ __launch_bounds__(128) void k_y1(const float* __restrict__ S1, const float* __restrict__ emb1,
                                            const float* __restrict__ c1b, float* __restrict__ ysum){
  int b = blockIdx.x, co = blockIdx.y, t = threadIdx.x;
  __shared__ float em[640];
  for(int i=t;i<640;i+=128) em[i] = emb1[i];
  __syncthreads();
  if(t < 121){
    const float* S = S1 + b*1280 + co*40;
    float acc = c1b[co];
    #pragma unroll
    for(int v=0;v<5;v++)
      #pragma unroll
      for(int k=0;k<8;k++) acc = fmaf(S[v*8+k], em[v*128 + t + k], acc);
    ysum[b*3872 + co*121 + t] = 0.5f*acc;
  }
}

__global__ __launch_bounds__(128) void k_y2(const float* __restrict__ S2, const float* __restrict__ emb2,
                                            const float* __restrict__ c2b, float* __restrict__ ysum){
  int b = blockIdx.x, co = blockIdx.y, t = threadIdx.x;
  __shared__ float em[8320];
  for(int i=t;i<8320;i+=128) em[i] = emb2[i];
  __syncthreads();
  if(t < 121){
    const float* S = S2 + (size_t)b*16640 + co*520;
    float acc = c2b[co];
    for(int v=0;v<65;v++){
      #pragma unroll
      for(int k=0;k<8;k++) acc = fmaf(S[v*8+k], em[v*128 + t + k], acc);
    }
    ysum[b*3872 + co*121 + t] += 0.5f*acc;
  }
}

// out[b][o] = sum_j ysum[b][j]*fcw[o][j] + fcb[o]
// grid (64 graphs, 4 output-quarters); 8-way k-split per output, LDS reduce.
__global__ __launch_bounds__(256) void k_fcxr(const float* __restrict__ ysum, const float* __restrict__ fcw,
                                              const float* __restrict__ fcb, float* __restrict__ out){
  __shared__ float part[256];
  int b = blockIdx.x, q = blockIdx.y, t = threadIdx.x;
  int ol = t >> 3;          // 0..31
  int o  = q*32 + ol;
  int slice = t & 7;        // 0..7, each covers 121 float4 = 484 floats
  const float4* ys = (const float4*)(ysum + b*3872) + slice*121;
  const float4* wr = (const float4*)(fcw + (size_t)o*3872) + slice*121;
  float acc = 0.f;
  for(int k=0;k<121;k++){
    float4 y = ys[k], w4 = wr[k];
    acc += y.x*w4.x + y.y*w4.y + y.z*w4.z + y.w*w4.w;
  }
  part[t] = acc;
  __syncthreads();
  if(slice == 0){
    float s = fcb[o];
    #pragma unroll
    for(int i=0;i<8;i++) s += part[ol*8 + i];
    out[b*128 + o] = s;
  }
}

extern "C" void kernel_launch(void* const* d_in, const int* in_sizes, int n_in,
                              void* d_out, int out_size, void* d_ws, size_t ws_size,
                              hipStream_t stream){
  const int*   g_rna = (const int*)  d_in[0];
  const int*   l_rna = (const int*)  d_in[1];
  const float* pro_x = (const float*)d_in[2];
  const int*   eidx  = (const int*)  d_in[3];
  const float* pro_w = (const float*)d_in[4];
  const int*   batch = (const int*)  d_in[5];
  const float* emb1  = (const float*)d_in[6];
  const float* emb2  = (const float*)d_in[7];
  const float* c1w   = (const float*)d_in[8];
  const float* c1b   = (const float*)d_in[9];
  const float* c2w   = (const float*)d_in[10];
  const float* c2b   = (const float*)d_in[11];
  const float* fcxw  = (const float*)d_in[12];
  const float* fcxb  = (const float*)d_in[13];
  const float* gcnw  = (const float*)d_in[14];
  const float* gcnb  = (const float*)d_in[15];
  const float* bnm   = (const float*)d_in[16];
  const float* bnv   = (const float*)d_in[17];
  const float* bnw   = (const float*)d_in[18];
  const float* bnb   = (const float*)d_in[19];
  const float* gwl   = (const float*)d_in[20];
  const float* gwr   = (const float*)d_in[21];
  const float* gatt  = (const float*)d_in[22];
  const float* gatb  = (const float*)d_in[23];
  const float* f1w   = (const float*)d_in[24];
  const float* f1b   = (const float*)d_in[25];
  const float* f2w   = (const float*)d_in[26];
  const float* f2b_  = (const float*)d_in[27];
  float* out = (float*)d_out;

  char* ws = (char*)d_ws;
  size_t off = 0;
  auto A = [&](size_t n)->char*{ char* p = ws + off; off = (off + n + 255) & ~(size_t)255; return p; };
  int*   cnt    = (int*)  A((size_t)N_NODES*4);
  int*   rowptr = (int*)  A((size_t)(N_NODES+1)*4);
  int*   fill   = (int*)  A((size_t)N_NODES*4);
  int*   s_src  = (int*)  A((size_t)N_EDGES*4);
  float* s_w    = (float*)A((size_t)N_EDGES*4);
  float* g_e    = (float*)A((size_t)N_EDGES*4);
  float* dinv   = (float*)A((size_t)N_NODES*4);
  float* hbuf   = (float*)A((size_t)N_NODES*33*4);
  float* xp1    = (float*)A((size_t)N_NODES*36*4);
  float* xl     = (float*)A((size_t)N_NODES*132*4);
  float* xr     = (float*)A((size_t)N_NODES*132*4);
  float* xp2    = (float*)A((size_t)N_NODES*132*4);
  int*   gstart = (int*)  A(64*4);
  int*   gend   = (int*)  A(64*4);
  float* pooledT= (float*)A(132*64*4);
  float* pp     = (float*)A((size_t)64*16*132*4);
  float* h1T    = (float*)A(1024*64*4);
  float* S1     = (float*)A((size_t)64*1280*4);
  float* S2     = (float*)A((size_t)64*16640*4);
  float* ysum   = (float*)A((size_t)64*3872*4);
  (void)ws_size; (void)in_sizes; (void)n_in; (void)out_size;

  // protein GNN pipeline
  k_init   <<<196, 256, 0, stream>>>(cnt, fill, gstart, gend);
  k_hist   <<<3125, 256, 0, stream>>>(eidx, cnt);
  k_scan   <<<1, 1024, 0, stream>>>(cnt, rowptr);
  k_scatter<<<3125, 256, 0, stream>>>(eidx, pro_w, rowptr, fill, s_src, s_w);
  k_deg    <<<196, 256, 0, stream>>>(rowptr, s_w, dinv);
  k_enorm  <<<3125, 256, 0, stream>>>(s_src, s_w, dinv, g_e);
  k_h      <<<196, 256, 0, stream>>>(pro_x, gcnw, hbuf);
  k_gcn    <<<7143, 256, 0, stream>>>(hbuf, rowptr, s_src, g_e, dinv, gcnb, bnm, bnv, bnw, bnb, xp1);
  k_gatlin <<<782, 256, 0, stream>>>(xp1, gwl, gwr, xl, xr);
  k_gat    <<<N_NODES, 128, 0, stream>>>(rowptr, s_src, xl, xr, gatt, gatb, xp2);
  k_bounds <<<196, 256, 0, stream>>>(batch, gstart, gend);
  k_poolp  <<<dim3(64,16), 128, 0, stream>>>(xp2, gstart, gend, pp);
  k_poolr  <<<64, 256, 0, stream>>>(pp, gstart, gend, pooledT);
  k_fc1    <<<256, 256, 0, stream>>>(pooledT, f1w, f1b, h1T);
  k_fc2    <<<32, 256, 0, stream>>>(h1T, f2w, f2b_, out);

  // RNA branches
  k_s1  <<<dim3(64,32), 64, 0, stream>>>(g_rna, c1w, S1);
  k_s2  <<<dim3(64,32), 64, 0, stream>>>(l_rna, c2w, S2);
  k_y1  <<<dim3(64,32), 128, 0, stream>>>(S1, emb1, c1b, ysum);
  k_y2  <<<dim3(64,32), 128, 0, stream>>>(S2, emb2, c2b, ysum);
  k_fcxr<<<dim3(64,4), 256, 0, stream>>>(ysum, fcxw, fcxb, out);
}